// Round 2
// baseline (3393.512 us; speedup 1.0000x reference)
//
#include <hip/hip_runtime.h>

#define G60 60
#define KN 13

// ---------------------------------------------------------------------------
// Pack W[o][c][k] -> Wt[(c*13+k)][o] so the conv inner loop loads 16
// consecutive o's per (c,k) from a wave-uniform address.
// ---------------------------------------------------------------------------
__global__ void pack_w_kern(const float* __restrict__ W,
                            float* __restrict__ Wt, int O, int C) {
    int idx = blockIdx.x * blockDim.x + threadIdx.x;
    int total = O * C * KN;
    if (idx >= total) return;
    int o = idx / (C * KN);
    int r = idx - o * (C * KN);   // c*13+k
    Wt[(size_t)r * O + o] = W[idx];
}

// ---------------------------------------------------------------------------
// Generic comb-conv: out[b,o,g] = act( sum_{c,k} X[b,c,nei[g,k]] * W[o,c,k] + bias )
// Block: 256 threads = 4 waves. Lanes own g (60 of 64 active), each wave owns
// OPT consecutive o's. X[b] slab staged to LDS in 128-channel tiles.
// ---------------------------------------------------------------------------
template <int OPT, bool BN, bool RELU, bool RESID>
__global__ void __launch_bounds__(256) conv_kern(
    const float* __restrict__ X,            // [B][C][60]
    const float* __restrict__ Wt,           // [(c*13+k)][O]
    const float* __restrict__ bias,
    const float* __restrict__ gamma,
    const float* __restrict__ beta,
    const float* __restrict__ resid,        // [B][O][60] (optional)
    const int* __restrict__ nei,            // [60*13]
    float* __restrict__ out,                // [B][O][60]
    int C, int O) {
    __shared__ float Xs[128 * 61];
    const int tid = threadIdx.x;
    const int lane = tid & 63;
    const int b = blockIdx.y;
    const int wq = __builtin_amdgcn_readfirstlane(tid >> 6);
    const int o0 = blockIdx.x * (OPT * 4) + wq * OPT;

    const int gl = (lane < G60) ? lane : 0;
    int col[KN];
#pragma unroll
    for (int k = 0; k < KN; ++k) col[k] = nei[gl * KN + k];

    float acc[OPT];
#pragma unroll
    for (int j = 0; j < OPT; ++j) acc[j] = 0.f;

    const float* Xb = X + (size_t)b * C * G60;

    for (int c0 = 0; c0 < C; c0 += 128) {
        const int ct = min(128, C - c0);
        __syncthreads();
        for (int i = tid; i < ct * G60; i += 256) {
            int r = i / G60;
            int g = i - r * G60;
            Xs[r * 61 + g] = Xb[(size_t)(c0 + r) * G60 + g];
        }
        __syncthreads();
        for (int c = 0; c < ct; ++c) {
            float xk[KN];
#pragma unroll
            for (int k = 0; k < KN; ++k) xk[k] = Xs[c * 61 + col[k]];
            const float* __restrict__ w0 = Wt + ((size_t)(c0 + c) * KN) * O + o0;
#pragma unroll
            for (int k = 0; k < KN; ++k) {
                const float* __restrict__ w = w0 + (size_t)k * O;
#pragma unroll
                for (int j = 0; j < OPT; ++j) acc[j] = fmaf(xk[k], w[j], acc[j]);
            }
        }
    }

    if (lane < G60) {
#pragma unroll
        for (int j = 0; j < OPT; ++j) {
            const int o = o0 + j;
            float v = acc[j] + bias[o];
            if (BN) v = v * gamma[o] + beta[o];
            if (RELU) v = fmaxf(v, 0.f);
            if (RESID) v += resid[((size_t)b * O + o) * G60 + lane];
            out[((size_t)b * O + o) * G60 + lane] = v;
        }
    }
}

// ---------------------------------------------------------------------------
// Finalize one net: eqv_pre = t + feats; inv = mean_g(eqv_pre);
// eqv = eqv_pre / max(||eqv_pre||_ch, 1e-4); inv /= max(||inv||, 1e-4).
// One block per b, 64 threads. Writes fp32 outputs + fp32 eqv for des2dr.
// ---------------------------------------------------------------------------
__global__ void __launch_bounds__(64) finalize_kern(
    const float* __restrict__ t,             // [B][32][60]
    const float* __restrict__ feats,         // [B][32][60]
    float* __restrict__ out_eqv,             // [B][32][60]
    float* __restrict__ out_inv,             // [B][32]
    float* __restrict__ eqvf) {              // [B][32][60] fp32 scratch
    const int b = blockIdx.x;
    __shared__ float E[32 * 60];
    __shared__ float gnorm[60];
    __shared__ float inv_pre[32];
    __shared__ float inv_nrm;
    const int tid = threadIdx.x;

    for (int i = tid; i < 32 * 60; i += 64) {
        E[i] = t[(size_t)b * 1920 + i] + feats[(size_t)b * 1920 + i];
    }
    __syncthreads();
    if (tid < 60) {
        float s = 0.f;
        for (int f = 0; f < 32; ++f) {
            float v = E[f * 60 + tid];
            s += v * v;
        }
        gnorm[tid] = fmaxf(sqrtf(s), 1e-4f);
    }
    if (tid < 32) {
        float s = 0.f;
        for (int g = 0; g < 60; ++g) s += E[tid * 60 + g];
        inv_pre[tid] = s / 60.f;
    }
    __syncthreads();
    if (tid == 0) {
        float s = 0.f;
        for (int f = 0; f < 32; ++f) s += inv_pre[f] * inv_pre[f];
        inv_nrm = fmaxf(sqrtf(s), 1e-4f);
    }
    __syncthreads();
    for (int i = tid; i < 1920; i += 64) {
        int f = i / 60;
        int g = i - f * 60;
        float v = E[i] / gnorm[g];
        eqvf[(size_t)b * 1920 + i] = v;
        out_eqv[(size_t)b * 1920 + i] = v;
        (void)f;
    }
    if (tid < 32) out_inv[b * 32 + tid] = inv_pre[tid] / inv_nrm;
}

// ---------------------------------------------------------------------------
// des2dr: cor[b,a] = sum_{f,g} eqv0[b,f,permu[a*60+g]] * eqv1[b,f,g]; argmax_a.
// One block per b, 64 threads (lane = a).
// ---------------------------------------------------------------------------
__global__ void __launch_bounds__(64) des2dr_kern(
    const float* __restrict__ e0f, const float* __restrict__ e1f,
    const int* __restrict__ permu, int* __restrict__ pre_int,
    float* __restrict__ out_pre) {
    const int b = blockIdx.x;
    __shared__ float X0[32 * 60];
    __shared__ float X1[32 * 60];
    __shared__ float cor[64];
    const int tid = threadIdx.x;
    for (int i = tid; i < 1920; i += 64) {
        X0[i] = e0f[(size_t)b * 1920 + i];
        X1[i] = e1f[(size_t)b * 1920 + i];
    }
    __syncthreads();
    float s = 0.f;
    if (tid < 60) {
        for (int g = 0; g < 60; ++g) {
            int p = permu[tid * 60 + g];
            for (int f = 0; f < 32; ++f) s += X0[f * 60 + p] * X1[f * 60 + g];
        }
    }
    cor[tid] = s;
    __syncthreads();
    if (tid == 0) {
        float best = cor[0];
        int bi = 0;
        for (int a = 1; a < 60; ++a) {
            if (cor[a] > best) { best = cor[a]; bi = a; }  // first-max = jnp.argmax
        }
        pre_int[b] = bi;
        out_pre[b] = (float)bi;
    }
}

// ---------------------------------------------------------------------------
// ability = mean(pre == true); also emit true_idx as fp32.
// ---------------------------------------------------------------------------
__global__ void __launch_bounds__(256) ability_kern(
    const int* __restrict__ pre_int, const int* __restrict__ true_idx,
    float* __restrict__ out_ability, float* __restrict__ out_true) {
    __shared__ int cnt[256];
    const int t = threadIdx.x;
    cnt[t] = (pre_int[t] == true_idx[t]) ? 1 : 0;
    out_true[t] = (float)true_idx[t];
    __syncthreads();
    for (int s = 128; s > 0; s >>= 1) {
        if (t < s) cnt[t] += cnt[t + s];
        __syncthreads();
    }
    if (t == 0) out_ability[0] = (float)cnt[0] / 256.0f;
}

extern "C" void kernel_launch(void* const* d_in, const int* in_sizes, int n_in,
                              void* d_out, int out_size, void* d_ws, size_t ws_size,
                              hipStream_t stream) {
    const float* feats0 = (const float*)d_in[0];
    const float* feats1 = (const float*)d_in[1];
    const int* true_idx = (const int*)d_in[2];
    const int* nei = (const int*)d_in[3];
    const int* permu = (const int*)d_in[4];
    const float* W_in = (const float*)d_in[5];
    const float* b_in = (const float*)d_in[6];
    const float* W1 = (const float*)d_in[7];
    const float* b1 = (const float*)d_in[8];
    const float* g1 = (const float*)d_in[9];
    const float* be1 = (const float*)d_in[10];
    const float* W2 = (const float*)d_in[11];
    const float* b2 = (const float*)d_in[12];
    const float* g2 = (const float*)d_in[13];
    const float* be2 = (const float*)d_in[14];
    const float* Wo = (const float*)d_in[15];
    const float* bo = (const float*)d_in[16];
    const float* go = (const float*)d_in[17];
    const float* beo = (const float*)d_in[18];

    float* out = (float*)d_out;
    const size_t SZF = (size_t)256 * 32 * 60;  // 491520
    float* out_f0 = out;
    float* out_f1 = out + SZF;
    float* out_e0 = out + 2 * SZF;
    float* out_e1 = out + 3 * SZF;
    float* out_i0 = out + 4 * SZF;
    float* out_i1 = out_i0 + 256 * 32;
    float* out_ab = out_i1 + 256 * 32;
    float* out_tr = out_ab + 1;
    float* out_pr = out_tr + 256;

    // Workspace layout (fp32): packed weights + intermediates (~84 MB)
    float* ws = (float*)d_ws;
    float* Wt_in = ws;                       // 32*13*256   = 106496
    float* Wt1 = Wt_in + 106496;             // 256*13*512  = 1703936
    float* Wt2 = Wt1 + 1703936;              // 512*13*256  = 1703936
    float* Wto = Wt2 + 1703936;              // 256*13*32   = 106496
    float* dbuf = Wto + 106496;              // 256*256*60  = 3932160
    float* fcbuf = dbuf + 3932160;           // 256*512*60  = 7864320
    float* sbuf = fcbuf + 7864320;           // 256*256*60  = 3932160
    float* tbuf = sbuf + 3932160;            // 256*32*60   = 491520
    float* e0f = tbuf + 491520;              // 491520
    float* e1f = e0f + 491520;               // 491520
    int* pre_int = (int*)(e1f + 491520);     // 256

    // --- pack weights ---
    {
        int tot;
        tot = 256 * 32 * KN;
        pack_w_kern<<<dim3((tot + 255) / 256), dim3(256), 0, stream>>>(W_in, Wt_in, 256, 32);
        tot = 512 * 256 * KN;
        pack_w_kern<<<dim3((tot + 255) / 256), dim3(256), 0, stream>>>(W1, Wt1, 512, 256);
        tot = 256 * 512 * KN;
        pack_w_kern<<<dim3((tot + 255) / 256), dim3(256), 0, stream>>>(W2, Wt2, 256, 512);
        tot = 32 * 256 * KN;
        pack_w_kern<<<dim3((tot + 255) / 256), dim3(256), 0, stream>>>(Wo, Wto, 32, 256);
    }

    // --- passthrough outputs (fp32) ---
    hipMemcpyAsync(out_f0, feats0, SZF * sizeof(float), hipMemcpyDeviceToDevice, stream);
    hipMemcpyAsync(out_f1, feats1, SZF * sizeof(float), hipMemcpyDeviceToDevice, stream);

    // --- net 0 / net 1 ---
    for (int net = 0; net < 2; ++net) {
        const float* feats = net ? feats1 : feats0;
        float* eqvf = net ? e1f : e0f;
        float* oe = net ? out_e1 : out_e0;
        float* oi = net ? out_i1 : out_i0;

        // conv_in: 32 -> 256, plain
        conv_kern<16, false, false, false>
            <<<dim3(256 / 64, 256), dim3(256), 0, stream>>>(
                feats, Wt_in, b_in, nullptr, nullptr, nullptr, nei, dbuf, 32, 256);
        // conv1: 256 -> 512, BN+ReLU
        conv_kern<16, true, true, false>
            <<<dim3(512 / 64, 256), dim3(256), 0, stream>>>(
                dbuf, Wt1, b1, g1, be1, nullptr, nei, fcbuf, 256, 512);
        // conv2: 512 -> 256, BN+ReLU, then + d residual
        conv_kern<16, true, true, true>
            <<<dim3(256 / 64, 256), dim3(256), 0, stream>>>(
                fcbuf, Wt2, b2, g2, be2, dbuf, nei, sbuf, 512, 256);
        // conv_out: 256 -> 32, BN+ReLU
        conv_kern<8, true, true, false>
            <<<dim3(1, 256), dim3(256), 0, stream>>>(
                sbuf, Wto, bo, go, beo, nullptr, nei, tbuf, 256, 32);
        // finalize: eqv/inv
        finalize_kern<<<dim3(256), dim3(64), 0, stream>>>(tbuf, feats, oe, oi, eqvf);
    }

    // --- des2dr + ability ---
    des2dr_kern<<<dim3(256), dim3(64), 0, stream>>>(e0f, e1f, permu, pre_int, out_pr);
    ability_kern<<<dim3(1), dim3(256), 0, stream>>>(pre_int, true_idx, out_ab, out_tr);

    (void)in_sizes; (void)n_in; (void)out_size; (void)ws_size;
}

// Round 3
// 1261.870 us; speedup vs baseline: 2.6893x; 2.6893x over previous
//
#include <hip/hip_runtime.h>

#define G60 60
#define KN 13

typedef unsigned int u32;
typedef unsigned short u16;
typedef short short8 __attribute__((ext_vector_type(8)));
typedef float f32x4 __attribute__((ext_vector_type(4)));

// ---- split-bf16 helpers ----------------------------------------------------
__device__ __forceinline__ u32 f32_to_packed(float v) {
    u32 u = __float_as_uint(v);
    u32 hi = (u + 0x7FFFu + ((u >> 16) & 1u)) >> 16;      // RNE bf16 of v
    float vhi = __uint_as_float(hi << 16);
    float lof = v - vhi;
    u32 ul = __float_as_uint(lof);
    u32 lo = (ul + 0x7FFFu + ((ul >> 16) & 1u)) >> 16;    // RNE bf16 of residual
    return (hi << 16) | lo;
}
__device__ __forceinline__ float packed_hi(u32 w) { return __uint_as_float(w & 0xFFFF0000u); }
__device__ __forceinline__ float packed_lo(u32 w) { return __uint_as_float(w << 16); }
__device__ __forceinline__ float packed_f32(u32 w) { return packed_hi(w) + packed_lo(w); }

// ---- split fp32 -> packed u32 ---------------------------------------------
__global__ void split_x_kern(const float* __restrict__ in, u32* __restrict__ out, int n) {
    int i = blockIdx.x * 256 + threadIdx.x;
    if (i < n) out[i] = f32_to_packed(in[i]);
}

// ---- pack W[o][c][k] -> MFMA B-fragment order, hi/lo bf16 arrays -----------
// r-order: r = ct*13*CT + kk*CT + cc  (CT = C-tile). Chunk t covers 32 r's
// with a single kk. Element id = ((t*NTt + nt)*64 + lane)*8 + j;
// k-in-chunk = (lane>>4)*8 + j; o = nt*16 + (lane&15).
__global__ void pack_w_kern(const float* __restrict__ W, u16* __restrict__ Whi,
                            u16* __restrict__ Wlo, int C, int O, int CT) {
    int id = blockIdx.x * 256 + threadIdx.x;
    int total = KN * C * O;
    if (id >= total) return;
    int j = id & 7;
    int lane = (id >> 3) & 63;
    int fragid = id >> 9;
    int NTt = O >> 4;
    int nt = fragid % NTt;
    int t = fragid / NTt;
    int SUBS = CT >> 5;
    int CPC = KN * SUBS;
    int ct = t / CPC;
    int tt = t - ct * CPC;
    int kk = tt / SUBS;
    int sub = tt - kk * SUBS;
    int q = lane >> 4, nl = lane & 15;
    int o = nt * 16 + nl;
    int c = ct * CT + sub * 32 + q * 8 + j;
    float v = W[((size_t)o * C + c) * KN + kk];
    u32 pw = f32_to_packed(v);
    Whi[id] = (u16)(pw >> 16);
    Wlo[id] = (u16)(pw & 0xFFFFu);
}

// ---- MFMA comb-conv --------------------------------------------------------
// Block: 256 thr = 4 waves = 2 b's x 2 M-halves. Wave: 2 M-tiles x NTB N-tiles.
// A gathered from LDS X-slab (stride 61), B streamed from frag-packed global.
template <int CT, int NTB, bool BNR, bool RESID>
__global__ void __launch_bounds__(256) mconv_kern(
    const u32* __restrict__ Xp,            // [B][C][60] packed
    const u16* __restrict__ Whi, const u16* __restrict__ Wlo,
    const float* __restrict__ bias, const float* __restrict__ gamma,
    const float* __restrict__ beta,
    const u32* __restrict__ resid,         // [B][O][60] packed (optional)
    const int* __restrict__ nei,
    u32* __restrict__ outp,                // [B][O][60] packed
    int C, int O) {
    constexpr int SUBS = CT >> 5;
    constexpr int CPC = KN * SUBS;
    __shared__ u32 Xs[2][CT * 61];
    const int tid = threadIdx.x;
    const int lane = tid & 63;
    const int w = tid >> 6;
    const int wb = w >> 1;       // which b in block
    const int wm = w & 1;        // which M-half
    const int q = lane >> 4;
    const int nl = lane & 15;
    const int b = blockIdx.y * 2 + wb;
    const int NTt = O >> 4;
    const int nt0 = blockIdx.x * NTB;

    int col[2][KN];
#pragma unroll
    for (int mt = 0; mt < 2; ++mt) {
        int g = (wm * 2 + mt) * 16 + nl;
        if (g >= G60) g = 0;
#pragma unroll
        for (int kk = 0; kk < KN; ++kk) col[mt][kk] = nei[g * KN + kk];
    }

    f32x4 acc[2][NTB];
#pragma unroll
    for (int mt = 0; mt < 2; ++mt)
#pragma unroll
        for (int nt = 0; nt < NTB; ++nt) acc[mt][nt] = (f32x4)(0.f);

    const int nct = C / CT;
    for (int ct = 0; ct < nct; ++ct) {
        __syncthreads();
        for (int i = tid; i < 2 * CT * G60; i += 256) {
            int bb = (i >= CT * G60) ? 1 : 0;
            int ii = i - bb * CT * G60;
            int cc = (ii * 17477) >> 20;   // ii/60, exact for ii<3840
            int gg = ii - cc * G60;
            Xs[bb][cc * 61 + gg] =
                Xp[((size_t)(blockIdx.y * 2 + bb) * C + (size_t)ct * CT + cc) * G60 + gg];
        }
        __syncthreads();
        const u32* xsb = Xs[wb];
#pragma unroll
        for (int kk = 0; kk < KN; ++kk) {
#pragma unroll
            for (int sub = 0; sub < SUBS; ++sub) {
                const int t = ct * CPC + kk * SUBS + sub;
                short8 bh[NTB], bl[NTB];
#pragma unroll
                for (int nt = 0; nt < NTB; ++nt) {
                    size_t fb = ((size_t)(t * NTt + nt0 + nt) * 64 + lane) * 8;
                    bh[nt] = *reinterpret_cast<const short8*>(Whi + fb);
                    bl[nt] = *reinterpret_cast<const short8*>(Wlo + fb);
                }
                short8 ah[2], al[2];
#pragma unroll
                for (int mt = 0; mt < 2; ++mt) {
                    const int base = (sub * 32 + q * 8) * 61 + col[mt][kk];
                    u32 xw[8];
#pragma unroll
                    for (int j = 0; j < 8; ++j) xw[j] = xsb[base + j * 61];
                    union { u32 u[4]; short8 v; } H, L;
#pragma unroll
                    for (int p = 0; p < 4; ++p) {
                        H.u[p] = (xw[2 * p + 1] & 0xFFFF0000u) | (xw[2 * p] >> 16);
                        L.u[p] = (xw[2 * p + 1] << 16) | (xw[2 * p] & 0xFFFFu);
                    }
                    ah[mt] = H.v;
                    al[mt] = L.v;
                }
#pragma unroll
                for (int nt = 0; nt < NTB; ++nt)
#pragma unroll
                    for (int mt = 0; mt < 2; ++mt)
                        acc[mt][nt] = __builtin_amdgcn_mfma_f32_16x16x32_bf16(
                            ah[mt], bh[nt], acc[mt][nt], 0, 0, 0);
#pragma unroll
                for (int nt = 0; nt < NTB; ++nt)
#pragma unroll
                    for (int mt = 0; mt < 2; ++mt)
                        acc[mt][nt] = __builtin_amdgcn_mfma_f32_16x16x32_bf16(
                            ah[mt], bl[nt], acc[mt][nt], 0, 0, 0);
#pragma unroll
                for (int nt = 0; nt < NTB; ++nt)
#pragma unroll
                    for (int mt = 0; mt < 2; ++mt)
                        acc[mt][nt] = __builtin_amdgcn_mfma_f32_16x16x32_bf16(
                            al[mt], bh[nt], acc[mt][nt], 0, 0, 0);
            }
        }
    }

    // epilogue: D row (M=g) = q*4+reg, col (N=o) = lane&15  [m89-verified]
#pragma unroll
    for (int nt = 0; nt < NTB; ++nt) {
        const int o = (nt0 + nt) * 16 + nl;
        const float bi = bias[o];
        float ga = 1.f, be = 0.f;
        if (BNR) { ga = gamma[o]; be = beta[o]; }
#pragma unroll
        for (int mt = 0; mt < 2; ++mt) {
            const int gb = (wm * 2 + mt) * 16 + q * 4;
#pragma unroll
            for (int r = 0; r < 4; ++r) {
                const int g = gb + r;
                if (g < G60) {
                    float v = acc[mt][nt][r] + bi;
                    if (BNR) v = fmaxf(v * ga + be, 0.f);
                    size_t oi = ((size_t)b * O + o) * G60 + g;
                    if (RESID) v += packed_f32(resid[oi]);
                    outp[oi] = f32_to_packed(v);
                }
            }
        }
    }
}

// ---- finalize: eqv/inv normalize (reads packed t) --------------------------
__global__ void __launch_bounds__(64) finalize_kern(
    const u32* __restrict__ t,               // [B][32][60] packed
    const float* __restrict__ feats,         // [B][32][60]
    float* __restrict__ out_eqv,             // [B][32][60]
    float* __restrict__ out_inv) {           // [B][32]
    const int b = blockIdx.x;
    __shared__ float E[32 * G60];
    __shared__ float gnorm[G60];
    __shared__ float inv_pre[32];
    __shared__ float inv_nrm;
    const int tid = threadIdx.x;

    for (int i = tid; i < 32 * G60; i += 64)
        E[i] = packed_f32(t[(size_t)b * 1920 + i]) + feats[(size_t)b * 1920 + i];
    __syncthreads();
    if (tid < G60) {
        float s = 0.f;
        for (int f = 0; f < 32; ++f) { float v = E[f * G60 + tid]; s += v * v; }
        gnorm[tid] = fmaxf(sqrtf(s), 1e-4f);
    }
    if (tid < 32) {
        float s = 0.f;
        for (int g = 0; g < G60; ++g) s += E[tid * G60 + g];
        inv_pre[tid] = s / 60.f;
    }
    __syncthreads();
    if (tid == 0) {
        float s = 0.f;
        for (int f = 0; f < 32; ++f) s += inv_pre[f] * inv_pre[f];
        inv_nrm = fmaxf(sqrtf(s), 1e-4f);
    }
    __syncthreads();
    for (int i = tid; i < 1920; i += 64) {
        int f = i / G60;
        int g = i - f * G60;
        out_eqv[(size_t)b * 1920 + i] = E[i] / gnorm[g];
    }
    if (tid < 32) out_inv[b * 32 + tid] = inv_pre[tid] / inv_nrm;
}

// ---- des2dr ----------------------------------------------------------------
__global__ void __launch_bounds__(64) des2dr_kern(
    const float* __restrict__ e0f, const float* __restrict__ e1f,
    const int* __restrict__ permu, int* __restrict__ pre_int,
    float* __restrict__ out_pre) {
    const int b = blockIdx.x;
    __shared__ float X0[32 * G60];
    __shared__ float X1[32 * G60];
    __shared__ float cor[64];
    const int tid = threadIdx.x;
    for (int i = tid; i < 1920; i += 64) {
        X0[i] = e0f[(size_t)b * 1920 + i];
        X1[i] = e1f[(size_t)b * 1920 + i];
    }
    __syncthreads();
    float s = 0.f;
    if (tid < G60) {
        for (int g = 0; g < G60; ++g) {
            int p = permu[tid * G60 + g];
            for (int f = 0; f < 32; ++f) s += X0[f * G60 + p] * X1[f * G60 + g];
        }
    }
    cor[tid] = s;
    __syncthreads();
    if (tid == 0) {
        float best = cor[0];
        int bi = 0;
        for (int a = 1; a < G60; ++a)
            if (cor[a] > best) { best = cor[a]; bi = a; }   // first-max = jnp.argmax
        pre_int[b] = bi;
        out_pre[b] = (float)bi;
    }
}

__global__ void __launch_bounds__(256) ability_kern(
    const int* __restrict__ pre_int, const int* __restrict__ true_idx,
    float* __restrict__ out_ability, float* __restrict__ out_true) {
    __shared__ int cnt[256];
    const int t = threadIdx.x;
    cnt[t] = (pre_int[t] == true_idx[t]) ? 1 : 0;
    out_true[t] = (float)true_idx[t];
    __syncthreads();
    for (int s = 128; s > 0; s >>= 1) {
        if (t < s) cnt[t] += cnt[t + s];
        __syncthreads();
    }
    if (t == 0) out_ability[0] = (float)cnt[0] / 256.0f;
}

extern "C" void kernel_launch(void* const* d_in, const int* in_sizes, int n_in,
                              void* d_out, int out_size, void* d_ws, size_t ws_size,
                              hipStream_t stream) {
    const float* feats0 = (const float*)d_in[0];
    const float* feats1 = (const float*)d_in[1];
    const int* true_idx = (const int*)d_in[2];
    const int* nei = (const int*)d_in[3];
    const int* permu = (const int*)d_in[4];
    const float* W_in = (const float*)d_in[5];
    const float* b_in = (const float*)d_in[6];
    const float* W1 = (const float*)d_in[7];
    const float* b1 = (const float*)d_in[8];
    const float* g1 = (const float*)d_in[9];
    const float* be1 = (const float*)d_in[10];
    const float* W2 = (const float*)d_in[11];
    const float* b2 = (const float*)d_in[12];
    const float* g2 = (const float*)d_in[13];
    const float* be2 = (const float*)d_in[14];
    const float* Wo = (const float*)d_in[15];
    const float* bo = (const float*)d_in[16];
    const float* go = (const float*)d_in[17];
    const float* beo = (const float*)d_in[18];

    float* out = (float*)d_out;
    const size_t SZF = (size_t)256 * 32 * G60;  // 491520
    float* out_f0 = out;
    float* out_f1 = out + SZF;
    float* out_e0 = out + 2 * SZF;
    float* out_e1 = out + 3 * SZF;
    float* out_i0 = out + 4 * SZF;
    float* out_i1 = out_i0 + 256 * 32;
    float* out_ab = out_i1 + 256 * 32;
    float* out_tr = out_ab + 1;
    float* out_pr = out_tr + 256;

    // ---- workspace layout (bytes, 256-aligned) ----
    char* p = (char*)d_ws;
    auto alloc = [&](size_t bytes) { char* r = p; p += (bytes + 255) & ~(size_t)255; return r; };
    const size_t NW_IN = (size_t)KN * 32 * 256;    // 106496
    const size_t NW_1 = (size_t)KN * 256 * 512;    // 1703936
    const size_t NW_2 = (size_t)KN * 512 * 256;    // 1703936
    const size_t NW_O = (size_t)KN * 256 * 32;     // 106496
    u16* Whi_in = (u16*)alloc(NW_IN * 2); u16* Wlo_in = (u16*)alloc(NW_IN * 2);
    u16* Whi_1 = (u16*)alloc(NW_1 * 2);   u16* Wlo_1 = (u16*)alloc(NW_1 * 2);
    u16* Whi_2 = (u16*)alloc(NW_2 * 2);   u16* Wlo_2 = (u16*)alloc(NW_2 * 2);
    u16* Whi_o = (u16*)alloc(NW_O * 2);   u16* Wlo_o = (u16*)alloc(NW_O * 2);
    u32* xp0 = (u32*)alloc(SZF * 4);
    u32* xp1 = (u32*)alloc(SZF * 4);
    u32* dbuf = (u32*)alloc((size_t)256 * 256 * G60 * 4);
    u32* fcbuf = (u32*)alloc((size_t)256 * 512 * G60 * 4);
    u32* sbuf = (u32*)alloc((size_t)256 * 256 * G60 * 4);
    u32* tbuf = fcbuf;  // alias: fcbuf is dead by conv_out time
    int* pre_int = (int*)alloc(256 * 4);

    // ---- pack weights (frag order) + split inputs ----
    pack_w_kern<<<dim3((KN * 32 * 256 + 255) / 256), dim3(256), 0, stream>>>(
        W_in, Whi_in, Wlo_in, 32, 256, 32);
    pack_w_kern<<<dim3((KN * 256 * 512 + 255) / 256), dim3(256), 0, stream>>>(
        W1, Whi_1, Wlo_1, 256, 512, 64);
    pack_w_kern<<<dim3((KN * 512 * 256 + 255) / 256), dim3(256), 0, stream>>>(
        W2, Whi_2, Wlo_2, 512, 256, 64);
    pack_w_kern<<<dim3((KN * 256 * 32 + 255) / 256), dim3(256), 0, stream>>>(
        Wo, Whi_o, Wlo_o, 256, 32, 64);
    split_x_kern<<<dim3((int)(SZF / 256)), dim3(256), 0, stream>>>(feats0, xp0, (int)SZF);
    split_x_kern<<<dim3((int)(SZF / 256)), dim3(256), 0, stream>>>(feats1, xp1, (int)SZF);

    // ---- passthrough outputs ----
    hipMemcpyAsync(out_f0, feats0, SZF * sizeof(float), hipMemcpyDeviceToDevice, stream);
    hipMemcpyAsync(out_f1, feats1, SZF * sizeof(float), hipMemcpyDeviceToDevice, stream);

    for (int net = 0; net < 2; ++net) {
        const u32* xp = net ? xp1 : xp0;
        const float* feats = net ? feats1 : feats0;
        float* oe = net ? out_e1 : out_e0;
        float* oi = net ? out_i1 : out_i0;

        // conv_in: 32 -> 256, plain bias
        mconv_kern<32, 4, false, false><<<dim3(4, 128), dim3(256), 0, stream>>>(
            xp, Whi_in, Wlo_in, b_in, nullptr, nullptr, nullptr, nei, dbuf, 32, 256);
        // conv1: 256 -> 512, BN+ReLU
        mconv_kern<64, 4, true, false><<<dim3(8, 128), dim3(256), 0, stream>>>(
            dbuf, Whi_1, Wlo_1, b1, g1, be1, nullptr, nei, fcbuf, 256, 512);
        // conv2: 512 -> 256, BN+ReLU + residual(dbuf)
        mconv_kern<64, 4, true, true><<<dim3(4, 128), dim3(256), 0, stream>>>(
            fcbuf, Whi_2, Wlo_2, b2, g2, be2, dbuf, nei, sbuf, 512, 256);
        // conv_out: 256 -> 32, BN+ReLU (tbuf aliases fcbuf, which is now dead)
        mconv_kern<64, 2, true, false><<<dim3(1, 128), dim3(256), 0, stream>>>(
            sbuf, Whi_o, Wlo_o, bo, go, beo, nullptr, nei, tbuf, 256, 32);
        // finalize: writes fp32 eqv (also consumed by des2dr) + inv
        finalize_kern<<<dim3(256), dim3(64), 0, stream>>>(tbuf, feats, oe, oi);
    }

    des2dr_kern<<<dim3(256), dim3(64), 0, stream>>>(out_e0, out_e1, permu, pre_int, out_pr);
    ability_kern<<<dim3(1), dim3(256), 0, stream>>>(pre_int, true_idx, out_ab, out_tr);

    (void)in_sizes; (void)n_in; (void)out_size; (void)ws_size;
}

// Round 5
// 1170.425 us; speedup vs baseline: 2.8994x; 1.0781x over previous
//
#include <hip/hip_runtime.h>

#define G60 60
#define KN 13

typedef unsigned int u32;
typedef unsigned short u16;
typedef short short8 __attribute__((ext_vector_type(8)));
typedef float f32x4 __attribute__((ext_vector_type(4)));
typedef float f32x16 __attribute__((ext_vector_type(16)));
typedef u32 u32x4 __attribute__((ext_vector_type(4)));

// ---- split-bf16 helpers ----------------------------------------------------
__device__ __forceinline__ u32 f32_to_packed(float v) {
    u32 u = __float_as_uint(v);
    u32 hi = (u + 0x7FFFu + ((u >> 16) & 1u)) >> 16;      // RNE bf16 of v
    float vhi = __uint_as_float(hi << 16);
    float lof = v - vhi;
    u32 ul = __float_as_uint(lof);
    u32 lo = (ul + 0x7FFFu + ((ul >> 16) & 1u)) >> 16;    // RNE bf16 of residual
    return (hi << 16) | lo;
}
__device__ __forceinline__ float packed_f32(u32 w) {
    return __uint_as_float(w & 0xFFFF0000u) + __uint_as_float(w << 16);
}

// ---- split fp32 -> packed u32 ---------------------------------------------
__global__ void split_x_kern(const float* __restrict__ in, u32* __restrict__ out, int n) {
    int i = blockIdx.x * 256 + threadIdx.x;
    if (i < n) out[i] = f32_to_packed(in[i]);
}

// ---- pack W[o][c][k] -> 32x32x16 MFMA B-fragment order, hi/lo planes -------
// chunk t = (ct*13 + kk)*SUBS + sub ; element id = ((t*NTt + nt)*64 + lane)*8 + j
// o = nt*32 + (lane&31); c = ct*CT + sub*16 + (lane>>5)*8 + j
__global__ void pack_w_kern(const float* __restrict__ W, u16* __restrict__ Whi,
                            u16* __restrict__ Wlo, int C, int O, int CT) {
    int id = blockIdx.x * 256 + threadIdx.x;
    int total = KN * C * O;
    if (id >= total) return;
    int j = id & 7;
    int lane = (id >> 3) & 63;
    int fid = id >> 9;
    int NTt = O >> 5;
    int nt = fid % NTt;
    int t = fid / NTt;
    int SUBS = CT >> 4;
    int sub = t % SUBS;
    int kk = (t / SUBS) % KN;
    int ct = t / (KN * SUBS);
    int q = lane >> 5, n = lane & 31;
    int o = nt * 32 + n;
    int c = ct * CT + sub * 16 + q * 8 + j;
    u32 pw = f32_to_packed(W[((size_t)o * C + c) * KN + kk]);
    Whi[id] = (u16)(pw >> 16);
    Wlo[id] = (u16)(pw & 0xFFFFu);
}

// ---- 32x32x16 MFMA comb-conv ----------------------------------------------
// Block: NSPL*2 waves = 2 bsplit x NSPL nsplit. Wave: mt=2 (one b, g 0-31/32-63)
// x NTB N-tiles of 32. A from transposed split-plane LDS (stride CT+8 u16,
// 16B-aligned rows) via single ds_read_b128 per frag; B streamed as dwordx4.
// OUTF32 path (K-split partials) offsets outf by blockIdx.z plane.
template <int CT, int NTB, int NSPL, bool BNR, bool RESID, bool OUTF32>
__global__ void __launch_bounds__(NSPL * 128, 3) mconv2(
    const u32* __restrict__ Xp,            // [B][C][60] packed
    const u16* __restrict__ Whi, const u16* __restrict__ Wlo,
    const float* __restrict__ bias, const float* __restrict__ gamma,
    const float* __restrict__ beta,
    const u32* __restrict__ resid,         // [B][O][60] packed (optional)
    const int* __restrict__ nei,
    u32* __restrict__ outp,                // packed out (if !OUTF32)
    float* __restrict__ outf,              // fp32 partial out (if OUTF32)
    int C, int O, int tpz) {
    constexpr int SUBS = CT >> 4;
    constexpr int STRIDE = CT + 8;         // u16; row = (CT+8)*2 bytes, 16B-aligned
    constexpr int THREADS = NSPL * 128;
    __shared__ u16 Xs[2 * 2 * G60 * STRIDE];
    const int tid = threadIdx.x;
    const int lane = tid & 63;
    const int w = tid >> 6;
    const int wbs = (NSPL == 2) ? (w >> 1) : w;   // bsplit index 0/1
    const int wn = (NSPL == 2) ? (w & 1) : 0;     // nsplit index
    const int q = lane >> 5;
    const int m = lane & 31;
    const int bpair = blockIdx.x;
    const int b = bpair * 2 + wbs;
    const int NTt = O >> 5;
    const int nt0 = ((int)blockIdx.y * NSPL + wn) * NTB;
    const int ct0 = (int)blockIdx.z * tpz;
    const int ct1 = ct0 + tpz;
    float* outfz = OUTF32 ? (outf + (size_t)blockIdx.z * ((size_t)256 * O * G60)) : nullptr;

    // gather columns for this wave's rows (mt=2 tiles of 32 g's)
    int rowoff[2][KN];                     // col*STRIDE (u16 units)
#pragma unroll
    for (int mt = 0; mt < 2; ++mt) {
        int g = mt * 32 + m;
        int gl = (g < G60) ? g : 0;
#pragma unroll
        for (int kk = 0; kk < KN; ++kk) rowoff[mt][kk] = nei[gl * KN + kk] * STRIDE;
    }
    const int pbase0 = (wbs * 2 + 0) * G60 * STRIDE;
    const int pbase1 = (wbs * 2 + 1) * G60 * STRIDE;

    f32x16 acc[2][NTB];
#pragma unroll
    for (int mt = 0; mt < 2; ++mt)
#pragma unroll
        for (int nt = 0; nt < NTB; ++nt) acc[mt][nt] = (f32x16)(0.f);

    for (int ct = ct0; ct < ct1; ++ct) {
        __syncthreads();
        // stage both b's, split planes, transposed [g][c]; cc in pairs for b32 writes
        constexpr int PPB = (CT / 2) * G60;    // pairs per b
        for (int i = tid; i < 2 * PPB; i += THREADS) {
            int bb = (i >= PPB) ? 1 : 0;
            int r = i - bb * PPB;
            int ccp = (r * 17477) >> 20;       // r/60 (exact for r<3840)
            int g = r - ccp * G60;
            int cc = ccp * 2;
            const u32* src = Xp + ((size_t)(bpair * 2 + bb) * C + (size_t)ct * CT + cc) * G60 + g;
            u32 w0 = src[0];
            u32 w1 = src[G60];
            int rb = (bb * 2) * G60 * STRIDE + g * STRIDE + cc;
            *(u32*)(Xs + rb) = (w0 >> 16) | (w1 & 0xFFFF0000u);             // hi plane
            *(u32*)(Xs + rb + G60 * STRIDE) = (w0 & 0xFFFFu) | (w1 << 16);  // lo plane
        }
        __syncthreads();
#pragma unroll
        for (int kk = 0; kk < KN; ++kk) {
#pragma unroll
            for (int sub = 0; sub < SUBS; ++sub) {
                const int t = (ct * KN + kk) * SUBS + sub;
                // B fragments
                short8 bh[NTB], bl[NTB];
#pragma unroll
                for (int nt = 0; nt < NTB; ++nt) {
                    size_t fb = ((size_t)(t * NTt + nt0 + nt) * 64 + lane) * 8;
                    bh[nt] = *reinterpret_cast<const short8*>(Whi + fb);
                    bl[nt] = *reinterpret_cast<const short8*>(Wlo + fb);
                }
                // A fragments: single b128 per (mt, plane)
                short8 ah[2], al[2];
#pragma unroll
                for (int mt = 0; mt < 2; ++mt) {
                    int off = rowoff[mt][kk] + sub * 16 + q * 8;
                    ah[mt] = *reinterpret_cast<const short8*>(Xs + pbase0 + off);
                    al[mt] = *reinterpret_cast<const short8*>(Xs + pbase1 + off);
                }
#pragma unroll
                for (int nt = 0; nt < NTB; ++nt)
#pragma unroll
                    for (int mt = 0; mt < 2; ++mt)
                        acc[mt][nt] = __builtin_amdgcn_mfma_f32_32x32x16_bf16(
                            ah[mt], bh[nt], acc[mt][nt], 0, 0, 0);
#pragma unroll
                for (int nt = 0; nt < NTB; ++nt)
#pragma unroll
                    for (int mt = 0; mt < 2; ++mt)
                        acc[mt][nt] = __builtin_amdgcn_mfma_f32_32x32x16_bf16(
                            ah[mt], bl[nt], acc[mt][nt], 0, 0, 0);
#pragma unroll
                for (int nt = 0; nt < NTB; ++nt)
#pragma unroll
                    for (int mt = 0; mt < 2; ++mt)
                        acc[mt][nt] = __builtin_amdgcn_mfma_f32_32x32x16_bf16(
                            al[mt], bh[nt], acc[mt][nt], 0, 0, 0);
            }
        }
    }

    // epilogue. C/D: col(o) = lane&31, row(g-in-tile) = (r&3) + 8*(r>>2) + 4*q
#pragma unroll
    for (int nt = 0; nt < NTB; ++nt) {
        const int o = (nt0 + nt) * 32 + m;
        float bi = 0.f, ga = 1.f, be = 0.f;
        if (!OUTF32) bi = bias[o];
        if (BNR) { ga = gamma[o]; be = beta[o]; }
#pragma unroll
        for (int mt = 0; mt < 2; ++mt) {
#pragma unroll
            for (int grp = 0; grp < 4; ++grp) {
                const int g0 = mt * 32 + grp * 8 + q * 4;
                if (g0 < G60) {
                    size_t oi = ((size_t)b * O + o) * G60 + g0;
                    if (OUTF32) {
                        f32x4 v;
#pragma unroll
                        for (int rr = 0; rr < 4; ++rr) v[rr] = acc[mt][nt][grp * 4 + rr];
                        *reinterpret_cast<f32x4*>(outfz + oi) = v;
                    } else {
                        u32x4 pv;
                        f32x4 rs;
                        if (RESID) rs = *reinterpret_cast<const f32x4*>(resid + oi);  // packed bits
#pragma unroll
                        for (int rr = 0; rr < 4; ++rr) {
                            float v = acc[mt][nt][grp * 4 + rr] + bi;
                            if (BNR) v = fmaxf(v * ga + be, 0.f);
                            if (RESID) v += packed_f32(__float_as_uint(rs[rr]));
                            pv[rr] = f32_to_packed(v);
                        }
                        *reinterpret_cast<u32x4*>(outp + oi) = pv;
                    }
                }
            }
        }
    }
}

// ---- finalize: sum 4 conv_out partials, BN+ReLU, +feats, norms -------------
__global__ void __launch_bounds__(64) finalize_kern(
    const float* __restrict__ pout,          // [4][B][32][60] fp32 partials
    const float* __restrict__ feats,         // [B][32][60]
    const float* __restrict__ bo, const float* __restrict__ go,
    const float* __restrict__ beo,
    float* __restrict__ out_eqv,             // [B][32][60]
    float* __restrict__ out_inv) {           // [B][32]
    const int b = blockIdx.x;
    const size_t PB = (size_t)256 * 32 * G60;
    __shared__ float E[32 * G60];
    __shared__ float gnorm[G60];
    __shared__ float inv_pre[32];
    __shared__ float inv_nrm;
    const int tid = threadIdx.x;

    for (int i = tid; i < 32 * G60; i += 64) {
        int f = i / G60;
        size_t idx = (size_t)b * 1920 + i;
        float s = pout[idx] + pout[PB + idx] + pout[2 * PB + idx] + pout[3 * PB + idx];
        float v = fmaxf((s + bo[f]) * go[f] + beo[f], 0.f);
        E[i] = v + feats[idx];
    }
    __syncthreads();
    if (tid < G60) {
        float s = 0.f;
        for (int f = 0; f < 32; ++f) { float v = E[f * G60 + tid]; s += v * v; }
        gnorm[tid] = fmaxf(sqrtf(s), 1e-4f);
    }
    if (tid < 32) {
        float s = 0.f;
        for (int g = 0; g < G60; ++g) s += E[tid * G60 + g];
        inv_pre[tid] = s / 60.f;
    }
    __syncthreads();
    if (tid == 0) {
        float s = 0.f;
        for (int f = 0; f < 32; ++f) s += inv_pre[f] * inv_pre[f];
        inv_nrm = fmaxf(sqrtf(s), 1e-4f);
    }
    __syncthreads();
    for (int i = tid; i < 1920; i += 64) {
        int g = i % G60;
        out_eqv[(size_t)b * 1920 + i] = E[i] / gnorm[g];
    }
    if (tid < 32) out_inv[b * 32 + tid] = inv_pre[tid] / inv_nrm;
}

// ---- des2dr ----------------------------------------------------------------
__global__ void __launch_bounds__(64) des2dr_kern(
    const float* __restrict__ e0f, const float* __restrict__ e1f,
    const int* __restrict__ permu, int* __restrict__ pre_int,
    float* __restrict__ out_pre) {
    const int b = blockIdx.x;
    __shared__ float X0[32 * G60];
    __shared__ float X1[32 * G60];
    __shared__ float cor[64];
    const int tid = threadIdx.x;
    for (int i = tid; i < 1920; i += 64) {
        X0[i] = e0f[(size_t)b * 1920 + i];
        X1[i] = e1f[(size_t)b * 1920 + i];
    }
    __syncthreads();
    float s = 0.f;
    if (tid < G60) {
        for (int g = 0; g < G60; ++g) {
            int p = permu[tid * G60 + g];
            for (int f = 0; f < 32; ++f) s += X0[f * G60 + p] * X1[f * G60 + g];
        }
    }
    cor[tid] = s;
    __syncthreads();
    if (tid == 0) {
        float best = cor[0];
        int bi = 0;
        for (int a = 1; a < G60; ++a)
            if (cor[a] > best) { best = cor[a]; bi = a; }   // first-max = jnp.argmax
        pre_int[b] = bi;
        out_pre[b] = (float)bi;
    }
}

__global__ void __launch_bounds__(256) ability_kern(
    const int* __restrict__ pre_int, const int* __restrict__ true_idx,
    float* __restrict__ out_ability, float* __restrict__ out_true) {
    __shared__ int cnt[256];
    const int t = threadIdx.x;
    cnt[t] = (pre_int[t] == true_idx[t]) ? 1 : 0;
    out_true[t] = (float)true_idx[t];
    __syncthreads();
    for (int s = 128; s > 0; s >>= 1) {
        if (t < s) cnt[t] += cnt[t + s];
        __syncthreads();
    }
    if (t == 0) out_ability[0] = (float)cnt[0] / 256.0f;
}

extern "C" void kernel_launch(void* const* d_in, const int* in_sizes, int n_in,
                              void* d_out, int out_size, void* d_ws, size_t ws_size,
                              hipStream_t stream) {
    const float* feats0 = (const float*)d_in[0];
    const float* feats1 = (const float*)d_in[1];
    const int* true_idx = (const int*)d_in[2];
    const int* nei = (const int*)d_in[3];
    const int* permu = (const int*)d_in[4];
    const float* W_in = (const float*)d_in[5];
    const float* b_in = (const float*)d_in[6];
    const float* W1 = (const float*)d_in[7];
    const float* b1 = (const float*)d_in[8];
    const float* g1 = (const float*)d_in[9];
    const float* be1 = (const float*)d_in[10];
    const float* W2 = (const float*)d_in[11];
    const float* b2 = (const float*)d_in[12];
    const float* g2 = (const float*)d_in[13];
    const float* be2 = (const float*)d_in[14];
    const float* Wo = (const float*)d_in[15];
    const float* bo = (const float*)d_in[16];
    const float* go = (const float*)d_in[17];
    const float* beo = (const float*)d_in[18];

    float* out = (float*)d_out;
    const size_t SZF = (size_t)256 * 32 * G60;  // 491520
    float* out_f0 = out;
    float* out_f1 = out + SZF;
    float* out_e0 = out + 2 * SZF;
    float* out_e1 = out + 3 * SZF;
    float* out_i0 = out + 4 * SZF;
    float* out_i1 = out_i0 + 256 * 32;
    float* out_ab = out_i1 + 256 * 32;
    float* out_tr = out_ab + 1;
    float* out_pr = out_tr + 256;

    // ---- workspace layout ----
    char* p = (char*)d_ws;
    auto alloc = [&](size_t bytes) { char* r = p; p += (bytes + 255) & ~(size_t)255; return r; };
    const size_t NW_IN = (size_t)KN * 32 * 256;
    const size_t NW_1 = (size_t)KN * 256 * 512;
    const size_t NW_2 = (size_t)KN * 512 * 256;
    const size_t NW_O = (size_t)KN * 256 * 32;
    u16* Whi_in = (u16*)alloc(NW_IN * 2); u16* Wlo_in = (u16*)alloc(NW_IN * 2);
    u16* Whi_1 = (u16*)alloc(NW_1 * 2);   u16* Wlo_1 = (u16*)alloc(NW_1 * 2);
    u16* Whi_2 = (u16*)alloc(NW_2 * 2);   u16* Wlo_2 = (u16*)alloc(NW_2 * 2);
    u16* Whi_o = (u16*)alloc(NW_O * 2);   u16* Wlo_o = (u16*)alloc(NW_O * 2);
    u32* xp0 = (u32*)alloc(SZF * 4);
    u32* xp1 = (u32*)alloc(SZF * 4);
    u32* dbuf = (u32*)alloc((size_t)256 * 256 * G60 * 4);
    u32* fcbuf = (u32*)alloc((size_t)256 * 512 * G60 * 4);
    u32* sbuf = (u32*)alloc((size_t)256 * 256 * G60 * 4);
    float* pout = (float*)alloc(4 * SZF * 4);
    int* pre_int = (int*)alloc(256 * 4);

    // ---- pack weights + split inputs ----
    pack_w_kern<<<dim3((KN * 32 * 256 + 255) / 256), dim3(256), 0, stream>>>(
        W_in, Whi_in, Wlo_in, 32, 256, 32);
    pack_w_kern<<<dim3((KN * 256 * 512 + 255) / 256), dim3(256), 0, stream>>>(
        W1, Whi_1, Wlo_1, 256, 512, 64);
    pack_w_kern<<<dim3((KN * 512 * 256 + 255) / 256), dim3(256), 0, stream>>>(
        W2, Whi_2, Wlo_2, 512, 256, 64);
    pack_w_kern<<<dim3((KN * 256 * 32 + 255) / 256), dim3(256), 0, stream>>>(
        Wo, Whi_o, Wlo_o, 256, 32, 64);
    split_x_kern<<<dim3((int)(SZF / 256)), dim3(256), 0, stream>>>(feats0, xp0, (int)SZF);
    split_x_kern<<<dim3((int)(SZF / 256)), dim3(256), 0, stream>>>(feats1, xp1, (int)SZF);

    // ---- passthrough outputs ----
    hipMemcpyAsync(out_f0, feats0, SZF * sizeof(float), hipMemcpyDeviceToDevice, stream);
    hipMemcpyAsync(out_f1, feats1, SZF * sizeof(float), hipMemcpyDeviceToDevice, stream);

    for (int net = 0; net < 2; ++net) {
        const u32* xp = net ? xp1 : xp0;
        const float* feats = net ? feats1 : feats0;
        float* oe = net ? out_e1 : out_e0;
        float* oi = net ? out_i1 : out_i0;

        // conv_in: 32 -> 256. grid: (bpair=128, nchunk=2)
        mconv2<32, 2, 2, false, false, false><<<dim3(128, 2, 1), dim3(256), 0, stream>>>(
            xp, Whi_in, Wlo_in, b_in, nullptr, nullptr, nullptr, nei, dbuf, nullptr, 32, 256, 1);
        // conv1: 256 -> 512, BN+ReLU. grid: (128, 4)
        mconv2<64, 2, 2, true, false, false><<<dim3(128, 4, 1), dim3(256), 0, stream>>>(
            dbuf, Whi_1, Wlo_1, b1, g1, be1, nullptr, nei, fcbuf, nullptr, 256, 512, 4);
        // conv2: 512 -> 256, BN+ReLU + residual(dbuf). grid: (128, 2)
        mconv2<64, 2, 2, true, true, false><<<dim3(128, 2, 1), dim3(256), 0, stream>>>(
            fcbuf, Whi_2, Wlo_2, b2, g2, be2, dbuf, nei, sbuf, nullptr, 512, 256, 8);
        // conv_out: 256 -> 32, pure GEMM partials, K-split z=4. grid: (128, 1, 4)
        mconv2<64, 1, 1, false, false, true><<<dim3(128, 1, 4), dim3(128), 0, stream>>>(
            sbuf, Whi_o, Wlo_o, nullptr, nullptr, nullptr, nullptr, nei, nullptr, pout, 256, 32, 1);
        // finalize: sum partials + BN/ReLU + feats + norms
        finalize_kern<<<dim3(256), dim3(64), 0, stream>>>(pout, feats, bo, go, beo, oe, oi);
    }

    des2dr_kern<<<dim3(256), dim3(64), 0, stream>>>(out_e0, out_e1, permu, pre_int, out_pr);
    ability_kern<<<dim3(1), dim3(256), 0, stream>>>(pre_int, true_idx, out_ab, out_tr);

    (void)in_sizes; (void)n_in; (void)out_size; (void)ws_size;
}

// Round 6
// 954.602 us; speedup vs baseline: 3.5549x; 1.2261x over previous
//
#include <hip/hip_runtime.h>

#define G60 60
#define KN 13

typedef unsigned int u32;
typedef unsigned short u16;
typedef short short8 __attribute__((ext_vector_type(8)));
typedef float f32x4 __attribute__((ext_vector_type(4)));
typedef float f32x16 __attribute__((ext_vector_type(16)));
typedef u32 u32x4 __attribute__((ext_vector_type(4)));

// ---- split-bf16 helpers ----------------------------------------------------
__device__ __forceinline__ u32 f32_to_packed(float v) {
    u32 u = __float_as_uint(v);
    u32 hi = (u + 0x7FFFu + ((u >> 16) & 1u)) >> 16;      // RNE bf16 of v
    float vhi = __uint_as_float(hi << 16);
    float lof = v - vhi;
    u32 ul = __float_as_uint(lof);
    u32 lo = (ul + 0x7FFFu + ((ul >> 16) & 1u)) >> 16;    // RNE bf16 of residual
    return (hi << 16) | lo;
}
__device__ __forceinline__ float packed_f32(u32 w) {
    return __uint_as_float(w & 0xFFFF0000u) + __uint_as_float(w << 16);
}

// ---- pack W[o][c][k] -> 32x32x16 MFMA B-fragment order, hi/lo planes -------
// chunk t = (ct*13 + kk)*SUBS + sub ; element id = ((t*NTt + nt)*64 + lane)*8 + j
// o = nt*32 + (lane&31); c = ct*CT + sub*16 + (lane>>5)*8 + j
__global__ void pack_w_kern(const float* __restrict__ W, u16* __restrict__ Whi,
                            u16* __restrict__ Wlo, int C, int O, int CT) {
    int id = blockIdx.x * 256 + threadIdx.x;
    int total = KN * C * O;
    if (id >= total) return;
    int j = id & 7;
    int lane = (id >> 3) & 63;
    int fid = id >> 9;
    int NTt = O >> 5;
    int nt = fid % NTt;
    int t = fid / NTt;
    int SUBS = CT >> 4;
    int sub = t % SUBS;
    int kk = (t / SUBS) % KN;
    int ct = t / (KN * SUBS);
    int q = lane >> 5, n = lane & 31;
    int o = nt * 32 + n;
    int c = ct * CT + sub * 16 + q * 8 + j;
    u32 pw = f32_to_packed(W[((size_t)o * C + c) * KN + kk]);
    Whi[id] = (u16)(pw >> 16);
    Wlo[id] = (u16)(pw & 0xFFFFu);
}

// ---- unified 32x32x16 MFMA comb-conv ---------------------------------------
// One batch per block. Waves: NSPL n-split x (2/MT) m-split.
// SRC: 0 = packed u32 input; 1 = fp32 input (pack inline);
//      2 = combine two fp32 K-split partials + BN+ReLU + packed residual.
// Epilogue: OUTF32 -> fp32 partial plane (indexed by blockIdx.z); else packed
// with bias (+BN+ReLU if BNR).
template <int CT, int NTB, int NSPL, int MT, int SRC, bool BNR, bool OUTF32>
__global__ void __launch_bounds__(NSPL*(2/MT)*64, 4) mconv3(
    const u32* __restrict__ Xp, const float* __restrict__ Xf,
    const float* __restrict__ pIn,         // [2][B][C][60] fp32 partials (SRC=2)
    const float* __restrict__ bnb, const float* __restrict__ bng,
    const float* __restrict__ bnB,
    const u32* __restrict__ resid,         // [B][C][60] packed (SRC=2)
    const u16* __restrict__ Whi, const u16* __restrict__ Wlo,
    const float* __restrict__ bias, const float* __restrict__ gamma,
    const float* __restrict__ beta,
    const int* __restrict__ nei,
    u32* __restrict__ outp, float* __restrict__ outf,
    int C, int O, int tpz) {
    constexpr int NW = NSPL * (2 / MT);
    constexpr int THREADS = NW * 64;
    constexpr int SUBS = CT >> 4;
    constexpr int STRIDE = CT + 8;         // u16; rows 16B-aligned
    __shared__ u16 Xs[2 * G60 * STRIDE];
    const int tid = threadIdx.x;
    const int lane = tid & 63;
    const int w = tid >> 6;
    const int wn = w % NSPL;
    const int wm = (MT == 2) ? 0 : (w / NSPL);
    const int q = lane >> 5;
    const int m = lane & 31;
    const int b = blockIdx.x;
    const int NTt = O >> 5;
    const int nt0 = ((int)blockIdx.y * NSPL + wn) * NTB;
    const int ct0 = (int)blockIdx.z * tpz;
    const size_t PLi = (size_t)256 * C * G60;
    float* outfz = OUTF32 ? (outf + (size_t)blockIdx.z * ((size_t)256 * O * G60)) : nullptr;

    int rowoff[MT][KN];
#pragma unroll
    for (int mt = 0; mt < MT; ++mt) {
        int g = (wm + mt) * 32 + m;
        int gl = (g < G60) ? g : 0;
#pragma unroll
        for (int kk = 0; kk < KN; ++kk) rowoff[mt][kk] = nei[gl * KN + kk] * STRIDE;
    }

    f32x16 acc[MT][NTB];
#pragma unroll
    for (int mt = 0; mt < MT; ++mt)
#pragma unroll
        for (int nt = 0; nt < NTB; ++nt) acc[mt][nt] = (f32x16)(0.f);

    for (int ct = ct0; ct < ct0 + tpz; ++ct) {
        __syncthreads();
        constexpr int PAIRS = (CT / 2) * G60;
        for (int i = tid; i < PAIRS; i += THREADS) {
            int ccp = (i * 17477) >> 20;   // i/60, exact for i<3840
            int g = i - ccp * G60;
            int cc = ccp * 2;
            size_t cg0 = ((size_t)b * C + (size_t)ct * CT + cc) * G60 + g;
            u32 w0, w1;
            if (SRC == 0) {
                w0 = Xp[cg0]; w1 = Xp[cg0 + G60];
            } else if (SRC == 1) {
                w0 = f32_to_packed(Xf[cg0]); w1 = f32_to_packed(Xf[cg0 + G60]);
            } else {
                int c0 = ct * CT + cc;
                float v0 = pIn[cg0] + pIn[PLi + cg0];
                float v1 = pIn[cg0 + G60] + pIn[PLi + cg0 + G60];
                v0 = fmaxf((v0 + bnb[c0]) * bng[c0] + bnB[c0], 0.f) + packed_f32(resid[cg0]);
                v1 = fmaxf((v1 + bnb[c0 + 1]) * bng[c0 + 1] + bnB[c0 + 1], 0.f) + packed_f32(resid[cg0 + G60]);
                w0 = f32_to_packed(v0); w1 = f32_to_packed(v1);
            }
            int rb = g * STRIDE + cc;
            *(u32*)(Xs + rb) = (w0 >> 16) | (w1 & 0xFFFF0000u);             // hi plane
            *(u32*)(Xs + rb + G60 * STRIDE) = (w0 & 0xFFFFu) | (w1 << 16);  // lo plane
        }
        __syncthreads();
#pragma unroll
        for (int kk = 0; kk < KN; ++kk) {
#pragma unroll
            for (int sub = 0; sub < SUBS; ++sub) {
                const int t = (ct * KN + kk) * SUBS + sub;
                short8 bh[NTB], bl[NTB];
#pragma unroll
                for (int nt = 0; nt < NTB; ++nt) {
                    size_t fb = ((size_t)(t * NTt + nt0 + nt) * 64 + lane) * 8;
                    bh[nt] = *reinterpret_cast<const short8*>(Whi + fb);
                    bl[nt] = *reinterpret_cast<const short8*>(Wlo + fb);
                }
                short8 ah[MT], al[MT];
#pragma unroll
                for (int mt = 0; mt < MT; ++mt) {
                    int off = rowoff[mt][kk] + sub * 16 + q * 8;
                    ah[mt] = *reinterpret_cast<const short8*>(Xs + off);
                    al[mt] = *reinterpret_cast<const short8*>(Xs + G60 * STRIDE + off);
                }
#pragma unroll
                for (int nt = 0; nt < NTB; ++nt)
#pragma unroll
                    for (int mt = 0; mt < MT; ++mt)
                        acc[mt][nt] = __builtin_amdgcn_mfma_f32_32x32x16_bf16(
                            ah[mt], bh[nt], acc[mt][nt], 0, 0, 0);
#pragma unroll
                for (int nt = 0; nt < NTB; ++nt)
#pragma unroll
                    for (int mt = 0; mt < MT; ++mt)
                        acc[mt][nt] = __builtin_amdgcn_mfma_f32_32x32x16_bf16(
                            ah[mt], bl[nt], acc[mt][nt], 0, 0, 0);
#pragma unroll
                for (int nt = 0; nt < NTB; ++nt)
#pragma unroll
                    for (int mt = 0; mt < MT; ++mt)
                        acc[mt][nt] = __builtin_amdgcn_mfma_f32_32x32x16_bf16(
                            al[mt], bh[nt], acc[mt][nt], 0, 0, 0);
            }
        }
    }

    // epilogue. C/D: col(o)=lane&31, row-in-tile = (r&3)+8*(r>>2)+4*q [m74/m101]
#pragma unroll
    for (int nt = 0; nt < NTB; ++nt) {
        const int o = (nt0 + nt) * 32 + m;
        float bi = 0.f, ga = 1.f, be = 0.f;
        if (!OUTF32) { bi = bias[o]; if (BNR) { ga = gamma[o]; be = beta[o]; } }
#pragma unroll
        for (int mt = 0; mt < MT; ++mt) {
#pragma unroll
            for (int grp = 0; grp < 4; ++grp) {
                const int g0 = (wm + mt) * 32 + grp * 8 + q * 4;
                if (g0 < G60) {
                    size_t oi = ((size_t)b * O + o) * G60 + g0;
                    if (OUTF32) {
                        f32x4 v;
#pragma unroll
                        for (int rr = 0; rr < 4; ++rr) v[rr] = acc[mt][nt][grp * 4 + rr];
                        *reinterpret_cast<f32x4*>(outfz + oi) = v;
                    } else {
                        u32x4 pv;
#pragma unroll
                        for (int rr = 0; rr < 4; ++rr) {
                            float v = acc[mt][nt][grp * 4 + rr] + bi;
                            if (BNR) v = fmaxf(v * ga + be, 0.f);
                            pv[rr] = f32_to_packed(v);
                        }
                        *reinterpret_cast<u32x4*>(outp + oi) = pv;
                    }
                }
            }
        }
    }
}

// ---- finalize: sum 4 conv_out partials, BN+ReLU, +feats, norms -------------
__global__ void __launch_bounds__(64) finalize_kern(
    const float* __restrict__ pout,          // [4][B][32][60] fp32 partials
    const float* __restrict__ feats,         // [B][32][60]
    const float* __restrict__ bo, const float* __restrict__ go,
    const float* __restrict__ beo,
    float* __restrict__ out_eqv,             // [B][32][60]
    float* __restrict__ out_inv) {           // [B][32]
    const int b = blockIdx.x;
    const size_t PB = (size_t)256 * 32 * G60;
    __shared__ float E[32 * G60];
    __shared__ float gnorm[G60];
    __shared__ float inv_pre[32];
    __shared__ float inv_nrm;
    const int tid = threadIdx.x;

    for (int i = tid; i < 32 * G60; i += 64) {
        int f = i / G60;
        size_t idx = (size_t)b * 1920 + i;
        float s = pout[idx] + pout[PB + idx] + pout[2 * PB + idx] + pout[3 * PB + idx];
        float v = fmaxf((s + bo[f]) * go[f] + beo[f], 0.f);
        E[i] = v + feats[idx];
    }
    __syncthreads();
    if (tid < G60) {
        float s = 0.f;
        for (int f = 0; f < 32; ++f) { float v = E[f * G60 + tid]; s += v * v; }
        gnorm[tid] = fmaxf(sqrtf(s), 1e-4f);
    }
    if (tid < 32) {
        float s = 0.f;
        for (int g = 0; g < G60; ++g) s += E[tid * G60 + g];
        inv_pre[tid] = s / 60.f;
    }
    __syncthreads();
    if (tid == 0) {
        float s = 0.f;
        for (int f = 0; f < 32; ++f) s += inv_pre[f] * inv_pre[f];
        inv_nrm = fmaxf(sqrtf(s), 1e-4f);
    }
    __syncthreads();
    for (int i = tid; i < 1920; i += 64) {
        int g = i % G60;
        out_eqv[(size_t)b * 1920 + i] = E[i] / gnorm[g];
    }
    if (tid < 32) out_inv[b * 32 + tid] = inv_pre[tid] / inv_nrm;
}

// ---- des2dr ----------------------------------------------------------------
__global__ void __launch_bounds__(64) des2dr_kern(
    const float* __restrict__ e0f, const float* __restrict__ e1f,
    const int* __restrict__ permu, int* __restrict__ pre_int,
    float* __restrict__ out_pre) {
    const int b = blockIdx.x;
    __shared__ float X0[32 * G60];
    __shared__ float X1[32 * G60];
    __shared__ float cor[64];
    const int tid = threadIdx.x;
    for (int i = tid; i < 1920; i += 64) {
        X0[i] = e0f[(size_t)b * 1920 + i];
        X1[i] = e1f[(size_t)b * 1920 + i];
    }
    __syncthreads();
    float s = 0.f;
    if (tid < G60) {
        for (int g = 0; g < G60; ++g) {
            int p = permu[tid * G60 + g];
            for (int f = 0; f < 32; ++f) s += X0[f * G60 + p] * X1[f * G60 + g];
        }
    }
    cor[tid] = s;
    __syncthreads();
    if (tid == 0) {
        float best = cor[0];
        int bi = 0;
        for (int a = 1; a < G60; ++a)
            if (cor[a] > best) { best = cor[a]; bi = a; }   // first-max = jnp.argmax
        pre_int[b] = bi;
        out_pre[b] = (float)bi;
    }
}

__global__ void __launch_bounds__(256) ability_kern(
    const int* __restrict__ pre_int, const int* __restrict__ true_idx,
    float* __restrict__ out_ability, float* __restrict__ out_true) {
    __shared__ int cnt[256];
    const int t = threadIdx.x;
    cnt[t] = (pre_int[t] == true_idx[t]) ? 1 : 0;
    out_true[t] = (float)true_idx[t];
    __syncthreads();
    for (int s = 128; s > 0; s >>= 1) {
        if (t < s) cnt[t] += cnt[t + s];
        __syncthreads();
    }
    if (t == 0) out_ability[0] = (float)cnt[0] / 256.0f;
}

extern "C" void kernel_launch(void* const* d_in, const int* in_sizes, int n_in,
                              void* d_out, int out_size, void* d_ws, size_t ws_size,
                              hipStream_t stream) {
    const float* feats0 = (const float*)d_in[0];
    const float* feats1 = (const float*)d_in[1];
    const int* true_idx = (const int*)d_in[2];
    const int* nei = (const int*)d_in[3];
    const int* permu = (const int*)d_in[4];
    const float* W_in = (const float*)d_in[5];
    const float* b_in = (const float*)d_in[6];
    const float* W1 = (const float*)d_in[7];
    const float* b1 = (const float*)d_in[8];
    const float* g1 = (const float*)d_in[9];
    const float* be1 = (const float*)d_in[10];
    const float* W2 = (const float*)d_in[11];
    const float* b2 = (const float*)d_in[12];
    const float* g2 = (const float*)d_in[13];
    const float* be2 = (const float*)d_in[14];
    const float* Wo = (const float*)d_in[15];
    const float* bo = (const float*)d_in[16];
    const float* go = (const float*)d_in[17];
    const float* beo = (const float*)d_in[18];

    float* out = (float*)d_out;
    const size_t SZF = (size_t)256 * 32 * G60;  // 491520
    float* out_f0 = out;
    float* out_f1 = out + SZF;
    float* out_e0 = out + 2 * SZF;
    float* out_e1 = out + 3 * SZF;
    float* out_i0 = out + 4 * SZF;
    float* out_i1 = out_i0 + 256 * 32;
    float* out_ab = out_i1 + 256 * 32;
    float* out_tr = out_ab + 1;
    float* out_pr = out_tr + 256;

    // ---- workspace layout (~106 MB) ----
    char* p = (char*)d_ws;
    auto alloc = [&](size_t bytes) { char* r = p; p += (bytes + 255) & ~(size_t)255; return r; };
    const size_t NW_IN = (size_t)KN * 32 * 256;
    const size_t NW_1 = (size_t)KN * 256 * 512;
    const size_t NW_2 = (size_t)KN * 512 * 256;
    const size_t NW_O = (size_t)KN * 256 * 32;
    u16* Whi_in = (u16*)alloc(NW_IN * 2); u16* Wlo_in = (u16*)alloc(NW_IN * 2);
    u16* Whi_1 = (u16*)alloc(NW_1 * 2);   u16* Wlo_1 = (u16*)alloc(NW_1 * 2);
    u16* Whi_2 = (u16*)alloc(NW_2 * 2);   u16* Wlo_2 = (u16*)alloc(NW_2 * 2);
    u16* Whi_o = (u16*)alloc(NW_O * 2);   u16* Wlo_o = (u16*)alloc(NW_O * 2);
    u32* dbuf = (u32*)alloc((size_t)256 * 256 * G60 * 4);    // conv_in out, packed
    u32* fcbuf = (u32*)alloc((size_t)256 * 512 * G60 * 4);   // conv1 out, packed
    float* p2 = (float*)alloc((size_t)2 * 256 * 256 * G60 * 4);  // conv2 K-split partials
    float* pout = (float*)alloc((size_t)4 * SZF * 4);        // conv_out K-split partials
    int* pre_int = (int*)alloc(256 * 4);

    // ---- pack weights ----
    pack_w_kern<<<dim3((KN * 32 * 256 + 255) / 256), dim3(256), 0, stream>>>(
        W_in, Whi_in, Wlo_in, 32, 256, 32);
    pack_w_kern<<<dim3((KN * 256 * 512 + 255) / 256), dim3(256), 0, stream>>>(
        W1, Whi_1, Wlo_1, 256, 512, 64);
    pack_w_kern<<<dim3((KN * 512 * 256 + 255) / 256), dim3(256), 0, stream>>>(
        W2, Whi_2, Wlo_2, 512, 256, 64);
    pack_w_kern<<<dim3((KN * 256 * 32 + 255) / 256), dim3(256), 0, stream>>>(
        Wo, Whi_o, Wlo_o, 256, 32, 64);

    // ---- passthrough outputs ----
    hipMemcpyAsync(out_f0, feats0, SZF * sizeof(float), hipMemcpyDeviceToDevice, stream);
    hipMemcpyAsync(out_f1, feats1, SZF * sizeof(float), hipMemcpyDeviceToDevice, stream);

    for (int net = 0; net < 2; ++net) {
        const float* feats = net ? feats1 : feats0;
        float* oe = net ? out_e1 : out_e0;
        float* oi = net ? out_i1 : out_i0;

        // conv_in: 32 -> 256, fp32 src packed inline, bias-only packed out.
        mconv3<32, 1, 2, 1, 1, false, false><<<dim3(256, 4, 1), dim3(256), 0, stream>>>(
            nullptr, feats, nullptr, nullptr, nullptr, nullptr, nullptr,
            Whi_in, Wlo_in, b_in, nullptr, nullptr, nei, dbuf, nullptr, 32, 256, 1);
        // conv1: 256 -> 512, BN+ReLU packed out.
        mconv3<64, 2, 2, 1, 0, true, false><<<dim3(256, 4, 1), dim3(256), 0, stream>>>(
            dbuf, nullptr, nullptr, nullptr, nullptr, nullptr, nullptr,
            Whi_1, Wlo_1, b1, g1, be1, nei, fcbuf, nullptr, 256, 512, 4);
        // conv2: 512 -> 256, pure GEMM fp32 partials, z=2 K-split.
        mconv3<64, 2, 2, 1, 0, false, true><<<dim3(256, 2, 2), dim3(256), 0, stream>>>(
            fcbuf, nullptr, nullptr, nullptr, nullptr, nullptr, nullptr,
            Whi_2, Wlo_2, nullptr, nullptr, nullptr, nei, nullptr, p2, 512, 256, 4);
        // conv_out: 256 -> 32. Staging fuses: p2 z-combine + b2/g2/be2 BN+ReLU
        // + residual(dbuf). fp32 partials z=4.
        mconv3<64, 1, 1, 1, 2, false, true><<<dim3(256, 1, 4), dim3(128), 0, stream>>>(
            nullptr, nullptr, p2, b2, g2, be2, dbuf,
            Whi_o, Wlo_o, nullptr, nullptr, nullptr, nei, nullptr, pout, 256, 32, 1);
        // finalize: sum partials + bo/go/beo BN+ReLU + feats + norms
        finalize_kern<<<dim3(256), dim3(64), 0, stream>>>(pout, feats, bo, go, beo, oe, oi);
    }

    des2dr_kern<<<dim3(256), dim3(64), 0, stream>>>(out_e0, out_e1, permu, pre_int, out_pr);
    ability_kern<<<dim3(1), dim3(256), 0, stream>>>(pre_int, true_idx, out_ab, out_tr);

    (void)in_sizes; (void)n_in; (void)out_size; (void)ws_size;
}

// Round 7
// 945.760 us; speedup vs baseline: 3.5881x; 1.0093x over previous
//
#include <hip/hip_runtime.h>

#define G60 60
#define KN 13

typedef unsigned int u32;
typedef unsigned short u16;
typedef short short8 __attribute__((ext_vector_type(8)));
typedef float f32x4 __attribute__((ext_vector_type(4)));
typedef float f32x16 __attribute__((ext_vector_type(16)));
typedef u32 u32x4 __attribute__((ext_vector_type(4)));

// ---- split-bf16 helpers ----------------------------------------------------
__device__ __forceinline__ u32 f32_to_packed(float v) {
    u32 u = __float_as_uint(v);
    u32 hi = (u + 0x7FFFu + ((u >> 16) & 1u)) >> 16;      // RNE bf16 of v
    float vhi = __uint_as_float(hi << 16);
    float lof = v - vhi;
    u32 ul = __float_as_uint(lof);
    u32 lo = (ul + 0x7FFFu + ((ul >> 16) & 1u)) >> 16;    // RNE bf16 of residual
    return (hi << 16) | lo;
}
__device__ __forceinline__ float packed_f32(u32 w) {
    return __uint_as_float(w & 0xFFFF0000u) + __uint_as_float(w << 16);
}

// ---- pack W[o][c][k] -> 32x32x16 MFMA B-fragment order, hi/lo planes -------
// chunk t = (ct*13 + kk)*SUBS + sub ; element id = ((t*NTt + nt)*64 + lane)*8 + j
// o = nt*32 + (lane&31); c = ct*CT + sub*16 + (lane>>5)*8 + j
__global__ void pack_w_kern(const float* __restrict__ W, u16* __restrict__ Whi,
                            u16* __restrict__ Wlo, int C, int O, int CT) {
    int id = blockIdx.x * 256 + threadIdx.x;
    int total = KN * C * O;
    if (id >= total) return;
    int j = id & 7;
    int lane = (id >> 3) & 63;
    int fid = id >> 9;
    int NTt = O >> 5;
    int nt = fid % NTt;
    int t = fid / NTt;
    int SUBS = CT >> 4;
    int sub = t % SUBS;
    int kk = (t / SUBS) % KN;
    int ct = t / (KN * SUBS);
    int q = lane >> 5, n = lane & 31;
    int o = nt * 32 + n;
    int c = ct * CT + sub * 16 + q * 8 + j;
    u32 pw = f32_to_packed(W[((size_t)o * C + c) * KN + kk]);
    Whi[id] = (u16)(pw >> 16);
    Wlo[id] = (u16)(pw & 0xFFFFu);
}

// ---- 32x32x16 MFMA comb-conv, software-pipelined ---------------------------
// One batch per block. NW waves, each covering BOTH m-tiles (M=64) and NTB
// N-tiles (N=32*NTB). Explicit double-buffered prefetch of next-step A/B
// fragments. SRC: 0 packed, 1 fp32 (pack inline), 2 combine-2-partials+BN+ReLU
// +residual. OUTF32: fp32 partial plane indexed by blockIdx.z.
template <int CT, int NTB, int NW, int SRC, bool BNR, bool OUTF32>
__global__ void __launch_bounds__(NW * 64, 2) mconv4(
    const u32* __restrict__ Xp, const float* __restrict__ Xf,
    const float* __restrict__ pIn,
    const float* __restrict__ bnb, const float* __restrict__ bng,
    const float* __restrict__ bnB,
    const u32* __restrict__ resid,
    const u16* __restrict__ Whi, const u16* __restrict__ Wlo,
    const float* __restrict__ bias, const float* __restrict__ gamma,
    const float* __restrict__ beta,
    const int* __restrict__ nei,
    u32* __restrict__ outp, float* __restrict__ outf,
    int C, int O, int tpz) {
    constexpr int SUBS = CT >> 4;
    constexpr int S = KN * SUBS;           // K-steps per ct
    constexpr int STRIDE = CT + 8;         // u16; rows 16B-aligned
    constexpr int THREADS = NW * 64;
    __shared__ u16 Xs[2 * G60 * STRIDE];
    const int tid = threadIdx.x;
    const int lane = tid & 63;
    const int wv = tid >> 6;
    const int q = lane >> 5;
    const int m = lane & 31;
    const int b = blockIdx.x;
    const int NTt = O >> 5;
    const int nt0 = ((int)blockIdx.y * NW + wv) * NTB;
    const int ct0 = (int)blockIdx.z * tpz;
    const size_t PLi = (size_t)256 * C * G60;
    float* outfz = OUTF32 ? (outf + (size_t)blockIdx.z * ((size_t)256 * O * G60)) : nullptr;

    int rowoff[2][KN];
#pragma unroll
    for (int mt = 0; mt < 2; ++mt) {
        int g = mt * 32 + m;
        int gl = (g < G60) ? g : 0;
#pragma unroll
        for (int kk = 0; kk < KN; ++kk) rowoff[mt][kk] = nei[gl * KN + kk] * STRIDE;
    }

    f32x16 acc[2][NTB];
#pragma unroll
    for (int mt = 0; mt < 2; ++mt)
#pragma unroll
        for (int nt = 0; nt < NTB; ++nt) acc[mt][nt] = (f32x16)(0.f);

    for (int ct = ct0; ct < ct0 + tpz; ++ct) {
        __syncthreads();
        constexpr int PAIRS = (CT / 2) * G60;
        for (int i = tid; i < PAIRS; i += THREADS) {
            int ccp = (i * 17477) >> 20;   // i/60, exact for i<3840
            int g = i - ccp * G60;
            int cc = ccp * 2;
            size_t cg0 = ((size_t)b * C + (size_t)ct * CT + cc) * G60 + g;
            u32 w0, w1;
            if (SRC == 0) {
                w0 = Xp[cg0]; w1 = Xp[cg0 + G60];
            } else if (SRC == 1) {
                w0 = f32_to_packed(Xf[cg0]); w1 = f32_to_packed(Xf[cg0 + G60]);
            } else {
                int c0 = ct * CT + cc;
                float v0 = pIn[cg0] + pIn[PLi + cg0];
                float v1 = pIn[cg0 + G60] + pIn[PLi + cg0 + G60];
                v0 = fmaxf((v0 + bnb[c0]) * bng[c0] + bnB[c0], 0.f) + packed_f32(resid[cg0]);
                v1 = fmaxf((v1 + bnb[c0 + 1]) * bng[c0 + 1] + bnB[c0 + 1], 0.f) + packed_f32(resid[cg0 + G60]);
                w0 = f32_to_packed(v0); w1 = f32_to_packed(v1);
            }
            int rb = g * STRIDE + cc;
            *(u32*)(Xs + rb) = (w0 >> 16) | (w1 & 0xFFFF0000u);             // hi plane
            *(u32*)(Xs + rb + G60 * STRIDE) = (w0 & 0xFFFFu) | (w1 << 16);  // lo plane
        }
        __syncthreads();

        const size_t fb0 = (size_t)(ct * S) * NTt * 512 + (size_t)nt0 * 512 + (size_t)lane * 8;
        short8 bh[2][NTB], bl[2][NTB], ah[2][2], al[2][2];
        auto LD = [&](int s, int pb) {
            const size_t fb = fb0 + (size_t)s * ((size_t)NTt * 512);
#pragma unroll
            for (int nt = 0; nt < NTB; ++nt) {
                bh[pb][nt] = *reinterpret_cast<const short8*>(Whi + fb + nt * 512);
                bl[pb][nt] = *reinterpret_cast<const short8*>(Wlo + fb + nt * 512);
            }
            const int kk = s / SUBS, sub = s - kk * SUBS;
#pragma unroll
            for (int mt = 0; mt < 2; ++mt) {
                const int off = rowoff[mt][kk] + sub * 16 + q * 8;
                ah[pb][mt] = *reinterpret_cast<const short8*>(Xs + off);
                al[pb][mt] = *reinterpret_cast<const short8*>(Xs + G60 * STRIDE + off);
            }
        };
        LD(0, 0);
#pragma unroll
        for (int s = 0; s < S; ++s) {
            const int cur = s & 1, nxt = cur ^ 1;
            if (s + 1 < S) LD(s + 1, nxt);
#pragma unroll
            for (int nt = 0; nt < NTB; ++nt)
#pragma unroll
                for (int mt = 0; mt < 2; ++mt)
                    acc[mt][nt] = __builtin_amdgcn_mfma_f32_32x32x16_bf16(
                        ah[cur][mt], bh[cur][nt], acc[mt][nt], 0, 0, 0);
#pragma unroll
            for (int nt = 0; nt < NTB; ++nt)
#pragma unroll
                for (int mt = 0; mt < 2; ++mt)
                    acc[mt][nt] = __builtin_amdgcn_mfma_f32_32x32x16_bf16(
                        ah[cur][mt], bl[cur][nt], acc[mt][nt], 0, 0, 0);
#pragma unroll
            for (int nt = 0; nt < NTB; ++nt)
#pragma unroll
                for (int mt = 0; mt < 2; ++mt)
                    acc[mt][nt] = __builtin_amdgcn_mfma_f32_32x32x16_bf16(
                        al[cur][mt], bh[cur][nt], acc[mt][nt], 0, 0, 0);
        }
    }

    // epilogue. C/D: col(o)=lane&31, row-in-tile = (r&3)+8*(r>>2)+4*q [m74/m101]
#pragma unroll
    for (int nt = 0; nt < NTB; ++nt) {
        const int o = (nt0 + nt) * 32 + m;
        float bi = 0.f, ga = 1.f, be = 0.f;
        if (!OUTF32) { bi = bias[o]; if (BNR) { ga = gamma[o]; be = beta[o]; } }
#pragma unroll
        for (int mt = 0; mt < 2; ++mt) {
#pragma unroll
            for (int grp = 0; grp < 4; ++grp) {
                const int g0 = mt * 32 + grp * 8 + q * 4;
                if (g0 < G60) {
                    size_t oi = ((size_t)b * O + o) * G60 + g0;
                    if (OUTF32) {
                        f32x4 v;
#pragma unroll
                        for (int rr = 0; rr < 4; ++rr) v[rr] = acc[mt][nt][grp * 4 + rr];
                        *reinterpret_cast<f32x4*>(outfz + oi) = v;
                    } else {
                        u32x4 pv;
#pragma unroll
                        for (int rr = 0; rr < 4; ++rr) {
                            float v = acc[mt][nt][grp * 4 + rr] + bi;
                            if (BNR) v = fmaxf(v * ga + be, 0.f);
                            pv[rr] = f32_to_packed(v);
                        }
                        *reinterpret_cast<u32x4*>(outp + oi) = pv;
                    }
                }
            }
        }
    }
}

// ---- finalize: sum 4 conv_out partials, BN+ReLU, +feats, norms -------------
__global__ void __launch_bounds__(64) finalize_kern(
    const float* __restrict__ pout,          // [4][B][32][60] fp32 partials
    const float* __restrict__ feats,         // [B][32][60]
    const float* __restrict__ bo, const float* __restrict__ go,
    const float* __restrict__ beo,
    float* __restrict__ out_eqv,             // [B][32][60]
    float* __restrict__ out_inv) {           // [B][32]
    const int b = blockIdx.x;
    const size_t PB = (size_t)256 * 32 * G60;
    __shared__ float E[32 * G60];
    __shared__ float gnorm[G60];
    __shared__ float inv_pre[32];
    __shared__ float inv_nrm;
    const int tid = threadIdx.x;

    for (int i = tid; i < 32 * G60; i += 64) {
        int f = i / G60;
        size_t idx = (size_t)b * 1920 + i;
        float s = pout[idx] + pout[PB + idx] + pout[2 * PB + idx] + pout[3 * PB + idx];
        float v = fmaxf((s + bo[f]) * go[f] + beo[f], 0.f);
        E[i] = v + feats[idx];
    }
    __syncthreads();
    if (tid < G60) {
        float s = 0.f;
        for (int f = 0; f < 32; ++f) { float v = E[f * G60 + tid]; s += v * v; }
        gnorm[tid] = fmaxf(sqrtf(s), 1e-4f);
    }
    if (tid < 32) {
        float s = 0.f;
        for (int g = 0; g < G60; ++g) s += E[tid * G60 + g];
        inv_pre[tid] = s / 60.f;
    }
    __syncthreads();
    if (tid == 0) {
        float s = 0.f;
        for (int f = 0; f < 32; ++f) s += inv_pre[f] * inv_pre[f];
        inv_nrm = fmaxf(sqrtf(s), 1e-4f);
    }
    __syncthreads();
    for (int i = tid; i < 1920; i += 64) {
        int g = i % G60;
        out_eqv[(size_t)b * 1920 + i] = E[i] / gnorm[g];
    }
    if (tid < 32) out_inv[b * 32 + tid] = inv_pre[tid] / inv_nrm;
}

// ---- des2dr ----------------------------------------------------------------
__global__ void __launch_bounds__(64) des2dr_kern(
    const float* __restrict__ e0f, const float* __restrict__ e1f,
    const int* __restrict__ permu, int* __restrict__ pre_int,
    float* __restrict__ out_pre) {
    const int b = blockIdx.x;
    __shared__ float X0[32 * G60];
    __shared__ float X1[32 * G60];
    __shared__ float cor[64];
    const int tid = threadIdx.x;
    for (int i = tid; i < 1920; i += 64) {
        X0[i] = e0f[(size_t)b * 1920 + i];
        X1[i] = e1f[(size_t)b * 1920 + i];
    }
    __syncthreads();
    float s = 0.f;
    if (tid < G60) {
        for (int g = 0; g < G60; ++g) {
            int p = permu[tid * G60 + g];
            for (int f = 0; f < 32; ++f) s += X0[f * G60 + p] * X1[f * G60 + g];
        }
    }
    cor[tid] = s;
    __syncthreads();
    if (tid == 0) {
        float best = cor[0];
        int bi = 0;
        for (int a = 1; a < G60; ++a)
            if (cor[a] > best) { best = cor[a]; bi = a; }   // first-max = jnp.argmax
        pre_int[b] = bi;
        out_pre[b] = (float)bi;
    }
}

__global__ void __launch_bounds__(256) ability_kern(
    const int* __restrict__ pre_int, const int* __restrict__ true_idx,
    float* __restrict__ out_ability, float* __restrict__ out_true) {
    __shared__ int cnt[256];
    const int t = threadIdx.x;
    cnt[t] = (pre_int[t] == true_idx[t]) ? 1 : 0;
    out_true[t] = (float)true_idx[t];
    __syncthreads();
    for (int s = 128; s > 0; s >>= 1) {
        if (t < s) cnt[t] += cnt[t + s];
        __syncthreads();
    }
    if (t == 0) out_ability[0] = (float)cnt[0] / 256.0f;
}

extern "C" void kernel_launch(void* const* d_in, const int* in_sizes, int n_in,
                              void* d_out, int out_size, void* d_ws, size_t ws_size,
                              hipStream_t stream) {
    const float* feats0 = (const float*)d_in[0];
    const float* feats1 = (const float*)d_in[1];
    const int* true_idx = (const int*)d_in[2];
    const int* nei = (const int*)d_in[3];
    const int* permu = (const int*)d_in[4];
    const float* W_in = (const float*)d_in[5];
    const float* b_in = (const float*)d_in[6];
    const float* W1 = (const float*)d_in[7];
    const float* b1 = (const float*)d_in[8];
    const float* g1 = (const float*)d_in[9];
    const float* be1 = (const float*)d_in[10];
    const float* W2 = (const float*)d_in[11];
    const float* b2 = (const float*)d_in[12];
    const float* g2 = (const float*)d_in[13];
    const float* be2 = (const float*)d_in[14];
    const float* Wo = (const float*)d_in[15];
    const float* bo = (const float*)d_in[16];
    const float* go = (const float*)d_in[17];
    const float* beo = (const float*)d_in[18];

    float* out = (float*)d_out;
    const size_t SZF = (size_t)256 * 32 * G60;  // 491520
    float* out_f0 = out;
    float* out_f1 = out + SZF;
    float* out_e0 = out + 2 * SZF;
    float* out_e1 = out + 3 * SZF;
    float* out_i0 = out + 4 * SZF;
    float* out_i1 = out_i0 + 256 * 32;
    float* out_ab = out_i1 + 256 * 32;
    float* out_tr = out_ab + 1;
    float* out_pr = out_tr + 256;

    // ---- workspace layout (~106 MB) ----
    char* p = (char*)d_ws;
    auto alloc = [&](size_t bytes) { char* r = p; p += (bytes + 255) & ~(size_t)255; return r; };
    const size_t NW_IN = (size_t)KN * 32 * 256;
    const size_t NW_1 = (size_t)KN * 256 * 512;
    const size_t NW_2 = (size_t)KN * 512 * 256;
    const size_t NW_O = (size_t)KN * 256 * 32;
    u16* Whi_in = (u16*)alloc(NW_IN * 2); u16* Wlo_in = (u16*)alloc(NW_IN * 2);
    u16* Whi_1 = (u16*)alloc(NW_1 * 2);   u16* Wlo_1 = (u16*)alloc(NW_1 * 2);
    u16* Whi_2 = (u16*)alloc(NW_2 * 2);   u16* Wlo_2 = (u16*)alloc(NW_2 * 2);
    u16* Whi_o = (u16*)alloc(NW_O * 2);   u16* Wlo_o = (u16*)alloc(NW_O * 2);
    u32* dbuf = (u32*)alloc((size_t)256 * 256 * G60 * 4);    // conv_in out, packed
    u32* fcbuf = (u32*)alloc((size_t)256 * 512 * G60 * 4);   // conv1 out, packed
    float* p2 = (float*)alloc((size_t)2 * 256 * 256 * G60 * 4);  // conv2 K-split partials
    float* pout = (float*)alloc((size_t)4 * SZF * 4);        // conv_out K-split partials
    int* pre_int = (int*)alloc(256 * 4);

    // ---- pack weights ----
    pack_w_kern<<<dim3((KN * 32 * 256 + 255) / 256), dim3(256), 0, stream>>>(
        W_in, Whi_in, Wlo_in, 32, 256, 32);
    pack_w_kern<<<dim3((KN * 256 * 512 + 255) / 256), dim3(256), 0, stream>>>(
        W1, Whi_1, Wlo_1, 256, 512, 64);
    pack_w_kern<<<dim3((KN * 512 * 256 + 255) / 256), dim3(256), 0, stream>>>(
        W2, Whi_2, Wlo_2, 512, 256, 64);
    pack_w_kern<<<dim3((KN * 256 * 32 + 255) / 256), dim3(256), 0, stream>>>(
        Wo, Whi_o, Wlo_o, 256, 32, 64);

    // ---- passthrough outputs ----
    hipMemcpyAsync(out_f0, feats0, SZF * sizeof(float), hipMemcpyDeviceToDevice, stream);
    hipMemcpyAsync(out_f1, feats1, SZF * sizeof(float), hipMemcpyDeviceToDevice, stream);

    for (int net = 0; net < 2; ++net) {
        const float* feats = net ? feats1 : feats0;
        float* oe = net ? out_e1 : out_e0;
        float* oi = net ? out_i1 : out_i0;

        // conv_in: 32 -> 256, fp32 src packed inline. CT=32,NTB=1,NW=2.
        mconv4<32, 1, 2, 1, false, false><<<dim3(256, 4, 1), dim3(128), 0, stream>>>(
            nullptr, feats, nullptr, nullptr, nullptr, nullptr, nullptr,
            Whi_in, Wlo_in, b_in, nullptr, nullptr, nei, dbuf, nullptr, 32, 256, 1);
        // conv1: 256 -> 512, BN+ReLU. CT=64,NTB=2,NW=2 -> wave M=64,N=64.
        mconv4<64, 2, 2, 0, true, false><<<dim3(256, 4, 1), dim3(128), 0, stream>>>(
            dbuf, nullptr, nullptr, nullptr, nullptr, nullptr, nullptr,
            Whi_1, Wlo_1, b1, g1, be1, nei, fcbuf, nullptr, 256, 512, 4);
        // conv2: 512 -> 256, fp32 partials z=2.
        mconv4<64, 2, 2, 0, false, true><<<dim3(256, 2, 2), dim3(128), 0, stream>>>(
            fcbuf, nullptr, nullptr, nullptr, nullptr, nullptr, nullptr,
            Whi_2, Wlo_2, nullptr, nullptr, nullptr, nei, nullptr, p2, 512, 256, 4);
        // conv_out: 256 -> 32. Staging fuses p2 combine + b2/g2/be2 BN+ReLU
        // + residual(dbuf). fp32 partials z=4. NW=1 (64-thr blocks).
        mconv4<64, 1, 1, 2, false, true><<<dim3(256, 1, 4), dim3(64), 0, stream>>>(
            nullptr, nullptr, p2, b2, g2, be2, dbuf,
            Whi_o, Wlo_o, nullptr, nullptr, nullptr, nei, nullptr, pout, 256, 32, 1);
        // finalize: sum partials + bo/go/beo BN+ReLU + feats + norms
        finalize_kern<<<dim3(256), dim3(64), 0, stream>>>(pout, feats, bo, go, beo, oe, oi);
    }

    des2dr_kern<<<dim3(256), dim3(64), 0, stream>>>(out_e0, out_e1, permu, pre_int, out_pr);
    ability_kern<<<dim3(1), dim3(256), 0, stream>>>(pre_int, true_idx, out_ab, out_tr);

    (void)in_sizes; (void)n_in; (void)out_size; (void)ws_size;
}

// Round 8
// 933.163 us; speedup vs baseline: 3.6366x; 1.0135x over previous
//
#include <hip/hip_runtime.h>

#define G60 60
#define KN 13

typedef unsigned int u32;
typedef unsigned short u16;
typedef short short8 __attribute__((ext_vector_type(8)));
typedef float f32x4 __attribute__((ext_vector_type(4)));
typedef float f32x16 __attribute__((ext_vector_type(16)));
typedef u32 u32x4 __attribute__((ext_vector_type(4)));

// compile-time for loop: every index is a literal -> registers guaranteed
template <int I> struct Ic { static constexpr int v = I; };
template <int I, int N, typename F>
__device__ __forceinline__ void sfor(F&& f) {
    if constexpr (I < N) { f(Ic<I>{}); sfor<I + 1, N>(f); }
}

// ---- split-bf16 helpers ----------------------------------------------------
__device__ __forceinline__ u32 f32_to_packed(float v) {
    u32 u = __float_as_uint(v);
    u32 hi = (u + 0x7FFFu + ((u >> 16) & 1u)) >> 16;      // RNE bf16 of v
    float vhi = __uint_as_float(hi << 16);
    float lof = v - vhi;
    u32 ul = __float_as_uint(lof);
    u32 lo = (ul + 0x7FFFu + ((ul >> 16) & 1u)) >> 16;    // RNE bf16 of residual
    return (hi << 16) | lo;
}
__device__ __forceinline__ float packed_f32(u32 w) {
    return __uint_as_float(w & 0xFFFF0000u) + __uint_as_float(w << 16);
}

// ---- pack W[o][c][k] -> 32x32x16 MFMA B-fragment order, hi/lo planes -------
// chunk t = (ct*13 + kk)*SUBS + sub ; element id = ((t*NTt + nt)*64 + lane)*8 + j
// o = nt*32 + (lane&31); c = ct*CT + sub*16 + (lane>>5)*8 + j
__global__ void pack_w_kern(const float* __restrict__ W, u16* __restrict__ Whi,
                            u16* __restrict__ Wlo, int C, int O, int CT) {
    int id = blockIdx.x * 256 + threadIdx.x;
    int total = KN * C * O;
    if (id >= total) return;
    int j = id & 7;
    int lane = (id >> 3) & 63;
    int fid = id >> 9;
    int NTt = O >> 5;
    int nt = fid % NTt;
    int t = fid / NTt;
    int SUBS = CT >> 4;
    int sub = t % SUBS;
    int kk = (t / SUBS) % KN;
    int ct = t / (KN * SUBS);
    int q = lane >> 5, n = lane & 31;
    int o = nt * 32 + n;
    int c = ct * CT + sub * 16 + q * 8 + j;
    u32 pw = f32_to_packed(W[((size_t)o * C + c) * KN + kk]);
    Whi[id] = (u16)(pw >> 16);
    Wlo[id] = (u16)(pw & 0xFFFFu);
}

// ---- 32x32x16 MFMA comb-conv, static register pipeline ---------------------
// One batch per block, NW waves (wave: M=64, N=32*NTB). K-loop in groups of 2
// steps: B double-buffered in regs (prefetch g+1 while computing g), A read
// batched per group from LDS. All pipeline indices compile-time via sfor.
// SRC: 0 packed, 1 fp32 (pack inline), 2 combine-2-fp32-partials+BN+ReLU+resid.
// OUTF32: fp32 partial plane indexed by blockIdx.z; RESID: epilogue +resid.
template <int CT, int NTB, int NW, int SRC, bool BNR, bool RESID, bool OUTF32>
__global__ void __launch_bounds__(NW * 64, 2) mconv5(
    const u32* __restrict__ Xp, const float* __restrict__ Xf,
    const float* __restrict__ pIn,
    const float* __restrict__ bnb, const float* __restrict__ bng,
    const float* __restrict__ bnB,
    const u32* __restrict__ resid,
    const u16* __restrict__ Whi, const u16* __restrict__ Wlo,
    const float* __restrict__ bias, const float* __restrict__ gamma,
    const float* __restrict__ beta,
    const int* __restrict__ nei,
    u32* __restrict__ outp, float* __restrict__ outf,
    int C, int O, int tpz) {
    constexpr int SUBS = CT >> 4;
    constexpr int S = KN * SUBS;           // K-steps per ct tile
    constexpr int NG = S / 2;              // groups of 2 steps (S always even)
    constexpr int STRIDE = CT + 8;         // u16; rows 16B-aligned
    constexpr int THREADS = NW * 64;
    __shared__ u16 Xs[2 * G60 * STRIDE];
    const int tid = threadIdx.x;
    const int lane = tid & 63;
    const int wv = tid >> 6;
    const int q = lane >> 5;
    const int m = lane & 31;
    const int b = blockIdx.x;
    const int NTt = O >> 5;
    const int nt0 = ((int)blockIdx.y * NW + wv) * NTB;
    const int ct0 = (int)blockIdx.z * tpz;
    const size_t PLi = (size_t)256 * C * G60;
    float* outfz = OUTF32 ? (outf + (size_t)blockIdx.z * ((size_t)256 * O * G60)) : nullptr;

    int rowoff[2][KN];
#pragma unroll
    for (int mt = 0; mt < 2; ++mt) {
        int g = mt * 32 + m;
        int gl = (g < G60) ? g : 0;
#pragma unroll
        for (int kk = 0; kk < KN; ++kk) rowoff[mt][kk] = nei[gl * KN + kk] * STRIDE;
    }

    f32x16 acc[2][NTB];
#pragma unroll
    for (int mt = 0; mt < 2; ++mt)
#pragma unroll
        for (int nt = 0; nt < NTB; ++nt) acc[mt][nt] = (f32x16)(0.f);

    // pipeline registers (all indices compile-time)
    short8 Bh[2][2][NTB], Bl[2][2][NTB];   // [buf][step-in-group][nt]
    short8 Ah[2][2], Al[2][2];             // [step-in-group][mt]

    for (int ct = ct0; ct < ct0 + tpz; ++ct) {
        const size_t fbase = ((size_t)(ct * S) * NTt + nt0) * 512 + (size_t)lane * 8;

        __syncthreads();
        constexpr int PAIRS = (CT / 2) * G60;
        for (int i = tid; i < PAIRS; i += THREADS) {
            int ccp = (i * 17477) >> 20;   // i/60, exact for i<3840
            int g = i - ccp * G60;
            int cc = ccp * 2;
            size_t cg0 = ((size_t)b * C + (size_t)ct * CT + cc) * G60 + g;
            u32 w0, w1;
            if (SRC == 0) {
                w0 = Xp[cg0]; w1 = Xp[cg0 + G60];
            } else if (SRC == 1) {
                w0 = f32_to_packed(Xf[cg0]); w1 = f32_to_packed(Xf[cg0 + G60]);
            } else {
                int c0 = ct * CT + cc;
                float v0 = pIn[cg0] + pIn[PLi + cg0];
                float v1 = pIn[cg0 + G60] + pIn[PLi + cg0 + G60];
                v0 = fmaxf((v0 + bnb[c0]) * bng[c0] + bnB[c0], 0.f) + packed_f32(resid[cg0]);
                v1 = fmaxf((v1 + bnb[c0 + 1]) * bng[c0 + 1] + bnB[c0 + 1], 0.f) + packed_f32(resid[cg0 + G60]);
                w0 = f32_to_packed(v0); w1 = f32_to_packed(v1);
            }
            int rb = g * STRIDE + cc;
            *(u32*)(Xs + rb) = (w0 >> 16) | (w1 & 0xFFFF0000u);             // hi plane
            *(u32*)(Xs + rb + G60 * STRIDE) = (w0 & 0xFFFFu) | (w1 << 16);  // lo plane
        }

        // issue group-0 B prefetch before the barrier (independent of LDS)
        sfor<0, 2>([&](auto uc) {
            constexpr int u = decltype(uc)::v;
            sfor<0, NTB>([&](auto nc) {
                constexpr int nt = decltype(nc)::v;
                const size_t fb = fbase + (size_t)(u * NTt + nt) * 512;
                Bh[0][u][nt] = *reinterpret_cast<const short8*>(Whi + fb);
                Bl[0][u][nt] = *reinterpret_cast<const short8*>(Wlo + fb);
            });
        });
        __syncthreads();

        sfor<0, NG>([&](auto gc) {
            constexpr int g = decltype(gc)::v;
            constexpr int pb = g & 1;
            // prefetch group g+1 B fragments (double-buffered)
            if constexpr (g + 1 < NG) {
                constexpr int pn = (g + 1) & 1;
                sfor<0, 2>([&](auto uc) {
                    constexpr int u = decltype(uc)::v;
                    constexpr int s = 2 * (g + 1) + u;
                    sfor<0, NTB>([&](auto nc) {
                        constexpr int nt = decltype(nc)::v;
                        const size_t fb = fbase + (size_t)(s * NTt + nt) * 512;
                        Bh[pn][u][nt] = *reinterpret_cast<const short8*>(Whi + fb);
                        Bl[pn][u][nt] = *reinterpret_cast<const short8*>(Wlo + fb);
                    });
                });
            }
            // batched A reads for group g (8 ds_read_b128)
            sfor<0, 2>([&](auto uc) {
                constexpr int u = decltype(uc)::v;
                constexpr int s = 2 * g + u;
                constexpr int kk = s / SUBS;
                constexpr int sub = s - kk * SUBS;
                sfor<0, 2>([&](auto mc) {
                    constexpr int mt = decltype(mc)::v;
                    const int off = rowoff[mt][kk] + sub * 16 + q * 8;
                    Ah[u][mt] = *reinterpret_cast<const short8*>(Xs + off);
                    Al[u][mt] = *reinterpret_cast<const short8*>(Xs + G60 * STRIDE + off);
                });
            });
            // 24 MFMAs for group g
            sfor<0, 2>([&](auto uc) {
                constexpr int u = decltype(uc)::v;
                sfor<0, NTB>([&](auto nc) {
                    constexpr int nt = decltype(nc)::v;
                    sfor<0, 2>([&](auto mc) {
                        constexpr int mt = decltype(mc)::v;
                        acc[mt][nt] = __builtin_amdgcn_mfma_f32_32x32x16_bf16(
                            Ah[u][mt], Bh[pb][u][nt], acc[mt][nt], 0, 0, 0);
                    });
                });
                sfor<0, NTB>([&](auto nc) {
                    constexpr int nt = decltype(nc)::v;
                    sfor<0, 2>([&](auto mc) {
                        constexpr int mt = decltype(mc)::v;
                        acc[mt][nt] = __builtin_amdgcn_mfma_f32_32x32x16_bf16(
                            Ah[u][mt], Bl[pb][u][nt], acc[mt][nt], 0, 0, 0);
                    });
                });
                sfor<0, NTB>([&](auto nc) {
                    constexpr int nt = decltype(nc)::v;
                    sfor<0, 2>([&](auto mc) {
                        constexpr int mt = decltype(mc)::v;
                        acc[mt][nt] = __builtin_amdgcn_mfma_f32_32x32x16_bf16(
                            Al[u][mt], Bh[pb][u][nt], acc[mt][nt], 0, 0, 0);
                    });
                });
            });
        });
    }

    // epilogue. C/D: col(o)=lane&31, row-in-tile = (r&3)+8*(r>>2)+4*q [m74/m101]
#pragma unroll
    for (int nt = 0; nt < NTB; ++nt) {
        const int o = (nt0 + nt) * 32 + m;
        float bi = 0.f, ga = 1.f, be = 0.f;
        if (!OUTF32) { bi = bias[o]; if (BNR) { ga = gamma[o]; be = beta[o]; } }
#pragma unroll
        for (int mt = 0; mt < 2; ++mt) {
#pragma unroll
            for (int grp = 0; grp < 4; ++grp) {
                const int g0 = mt * 32 + grp * 8 + q * 4;
                if (g0 < G60) {
                    size_t oi = ((size_t)b * O + o) * G60 + g0;
                    if (OUTF32) {
                        f32x4 v;
#pragma unroll
                        for (int rr = 0; rr < 4; ++rr) v[rr] = acc[mt][nt][grp * 4 + rr];
                        *reinterpret_cast<f32x4*>(outfz + oi) = v;
                    } else {
                        u32x4 pv;
                        u32x4 rs;
                        if (RESID) rs = *reinterpret_cast<const u32x4*>(resid + oi);
#pragma unroll
                        for (int rr = 0; rr < 4; ++rr) {
                            float v = acc[mt][nt][grp * 4 + rr] + bi;
                            if (BNR) v = fmaxf(v * ga + be, 0.f);
                            if (RESID) v += packed_f32(rs[rr]);
                            pv[rr] = f32_to_packed(v);
                        }
                        *reinterpret_cast<u32x4*>(outp + oi) = pv;
                    }
                }
            }
        }
    }
}

// ---- finalize: sum 4 conv_out partials, BN+ReLU, +feats, norms -------------
__global__ void __launch_bounds__(64) finalize_kern(
    const float* __restrict__ pout,          // [4][B][32][60] fp32 partials
    const float* __restrict__ feats,         // [B][32][60]
    const float* __restrict__ bo, const float* __restrict__ go,
    const float* __restrict__ beo,
    float* __restrict__ out_eqv,             // [B][32][60]
    float* __restrict__ out_inv) {           // [B][32]
    const int b = blockIdx.x;
    const size_t PB = (size_t)256 * 32 * G60;
    __shared__ float E[32 * G60];
    __shared__ float gnorm[G60];
    __shared__ float inv_pre[32];
    __shared__ float inv_nrm;
    const int tid = threadIdx.x;

    for (int i = tid; i < 32 * G60; i += 64) {
        int f = i / G60;
        size_t idx = (size_t)b * 1920 + i;
        float s = pout[idx] + pout[PB + idx] + pout[2 * PB + idx] + pout[3 * PB + idx];
        float v = fmaxf((s + bo[f]) * go[f] + beo[f], 0.f);
        E[i] = v + feats[idx];
    }
    __syncthreads();
    if (tid < G60) {
        float s = 0.f;
        for (int f = 0; f < 32; ++f) { float v = E[f * G60 + tid]; s += v * v; }
        gnorm[tid] = fmaxf(sqrtf(s), 1e-4f);
    }
    if (tid < 32) {
        float s = 0.f;
        for (int g = 0; g < G60; ++g) s += E[tid * G60 + g];
        inv_pre[tid] = s / 60.f;
    }
    __syncthreads();
    if (tid == 0) {
        float s = 0.f;
        for (int f = 0; f < 32; ++f) s += inv_pre[f] * inv_pre[f];
        inv_nrm = fmaxf(sqrtf(s), 1e-4f);
    }
    __syncthreads();
    for (int i = tid; i < 1920; i += 64) {
        int g = i % G60;
        out_eqv[(size_t)b * 1920 + i] = E[i] / gnorm[g];
    }
    if (tid < 32) out_inv[b * 32 + tid] = inv_pre[tid] / inv_nrm;
}

// ---- des2dr ----------------------------------------------------------------
__global__ void __launch_bounds__(64) des2dr_kern(
    const float* __restrict__ e0f, const float* __restrict__ e1f,
    const int* __restrict__ permu, int* __restrict__ pre_int,
    float* __restrict__ out_pre) {
    const int b = blockIdx.x;
    __shared__ float X0[32 * G60];
    __shared__ float X1[32 * G60];
    __shared__ float cor[64];
    const int tid = threadIdx.x;
    for (int i = tid; i < 1920; i += 64) {
        X0[i] = e0f[(size_t)b * 1920 + i];
        X1[i] = e1f[(size_t)b * 1920 + i];
    }
    __syncthreads();
    float s = 0.f;
    if (tid < G60) {
        for (int g = 0; g < G60; ++g) {
            int p = permu[tid * G60 + g];
            for (int f = 0; f < 32; ++f) s += X0[f * G60 + p] * X1[f * G60 + g];
        }
    }
    cor[tid] = s;
    __syncthreads();
    if (tid == 0) {
        float best = cor[0];
        int bi = 0;
        for (int a = 1; a < G60; ++a)
            if (cor[a] > best) { best = cor[a]; bi = a; }   // first-max = jnp.argmax
        pre_int[b] = bi;
        out_pre[b] = (float)bi;
    }
}

__global__ void __launch_bounds__(256) ability_kern(
    const int* __restrict__ pre_int, const int* __restrict__ true_idx,
    float* __restrict__ out_ability, float* __restrict__ out_true) {
    __shared__ int cnt[256];
    const int t = threadIdx.x;
    cnt[t] = (pre_int[t] == true_idx[t]) ? 1 : 0;
    out_true[t] = (float)true_idx[t];
    __syncthreads();
    for (int s = 128; s > 0; s >>= 1) {
        if (t < s) cnt[t] += cnt[t + s];
        __syncthreads();
    }
    if (t == 0) out_ability[0] = (float)cnt[0] / 256.0f;
}

extern "C" void kernel_launch(void* const* d_in, const int* in_sizes, int n_in,
                              void* d_out, int out_size, void* d_ws, size_t ws_size,
                              hipStream_t stream) {
    const float* feats0 = (const float*)d_in[0];
    const float* feats1 = (const float*)d_in[1];
    const int* true_idx = (const int*)d_in[2];
    const int* nei = (const int*)d_in[3];
    const int* permu = (const int*)d_in[4];
    const float* W_in = (const float*)d_in[5];
    const float* b_in = (const float*)d_in[6];
    const float* W1 = (const float*)d_in[7];
    const float* b1 = (const float*)d_in[8];
    const float* g1 = (const float*)d_in[9];
    const float* be1 = (const float*)d_in[10];
    const float* W2 = (const float*)d_in[11];
    const float* b2 = (const float*)d_in[12];
    const float* g2 = (const float*)d_in[13];
    const float* be2 = (const float*)d_in[14];
    const float* Wo = (const float*)d_in[15];
    const float* bo = (const float*)d_in[16];
    const float* go = (const float*)d_in[17];
    const float* beo = (const float*)d_in[18];

    float* out = (float*)d_out;
    const size_t SZF = (size_t)256 * 32 * G60;  // 491520
    float* out_f0 = out;
    float* out_f1 = out + SZF;
    float* out_e0 = out + 2 * SZF;
    float* out_e1 = out + 3 * SZF;
    float* out_i0 = out + 4 * SZF;
    float* out_i1 = out_i0 + 256 * 32;
    float* out_ab = out_i1 + 256 * 32;
    float* out_tr = out_ab + 1;
    float* out_pr = out_tr + 256;

    // ---- workspace layout (~107 MB) ----
    char* p = (char*)d_ws;
    auto alloc = [&](size_t bytes) { char* r = p; p += (bytes + 255) & ~(size_t)255; return r; };
    const size_t NW_IN = (size_t)KN * 32 * 256;
    const size_t NW_1 = (size_t)KN * 256 * 512;
    const size_t NW_2 = (size_t)KN * 512 * 256;
    const size_t NW_O = (size_t)KN * 256 * 32;
    u16* Whi_in = (u16*)alloc(NW_IN * 2); u16* Wlo_in = (u16*)alloc(NW_IN * 2);
    u16* Whi_1 = (u16*)alloc(NW_1 * 2);   u16* Wlo_1 = (u16*)alloc(NW_1 * 2);
    u16* Whi_2 = (u16*)alloc(NW_2 * 2);   u16* Wlo_2 = (u16*)alloc(NW_2 * 2);
    u16* Whi_o = (u16*)alloc(NW_O * 2);   u16* Wlo_o = (u16*)alloc(NW_O * 2);
    u32* dbuf = (u32*)alloc((size_t)256 * 256 * G60 * 4);        // conv_in out, packed
    u32* fcbuf = (u32*)alloc((size_t)256 * 512 * G60 * 4);       // conv1 out, packed
    float* p2 = (float*)alloc((size_t)2 * 256 * 256 * G60 * 4);  // conv2 K-split partials
    float* pout = (float*)alloc((size_t)4 * SZF * 4);            // conv_out K-split partials
    int* pre_int = (int*)alloc(256 * 4);

    // ---- pack weights ----
    pack_w_kern<<<dim3((KN * 32 * 256 + 255) / 256), dim3(256), 0, stream>>>(
        W_in, Whi_in, Wlo_in, 32, 256, 32);
    pack_w_kern<<<dim3((KN * 256 * 512 + 255) / 256), dim3(256), 0, stream>>>(
        W1, Whi_1, Wlo_1, 256, 512, 64);
    pack_w_kern<<<dim3((KN * 512 * 256 + 255) / 256), dim3(256), 0, stream>>>(
        W2, Whi_2, Wlo_2, 512, 256, 64);
    pack_w_kern<<<dim3((KN * 256 * 32 + 255) / 256), dim3(256), 0, stream>>>(
        Wo, Whi_o, Wlo_o, 256, 32, 64);

    // ---- passthrough outputs ----
    hipMemcpyAsync(out_f0, feats0, SZF * sizeof(float), hipMemcpyDeviceToDevice, stream);
    hipMemcpyAsync(out_f1, feats1, SZF * sizeof(float), hipMemcpyDeviceToDevice, stream);

    for (int net = 0; net < 2; ++net) {
        const float* feats = net ? feats1 : feats0;
        float* oe = net ? out_e1 : out_e0;
        float* oi = net ? out_i1 : out_i0;

        // conv_in: 32 -> 256, fp32 src packed inline. grid (256,4).
        mconv5<32, 1, 2, 1, false, false, false><<<dim3(256, 4, 1), dim3(128), 0, stream>>>(
            nullptr, feats, nullptr, nullptr, nullptr, nullptr, nullptr,
            Whi_in, Wlo_in, b_in, nullptr, nullptr, nei, dbuf, nullptr, 32, 256, 1);
        // conv1: 256 -> 512, BN+ReLU fused epilogue. grid (256,4).
        mconv5<64, 2, 2, 0, true, false, false><<<dim3(256, 4, 1), dim3(128), 0, stream>>>(
            dbuf, nullptr, nullptr, nullptr, nullptr, nullptr, nullptr,
            Whi_1, Wlo_1, b1, g1, be1, nei, fcbuf, nullptr, 256, 512, 4);
        // conv2: 512 -> 256, fp32 partials, z=2 K-split. grid (256,2,2).
        mconv5<64, 2, 2, 0, false, false, true><<<dim3(256, 2, 2), dim3(128), 0, stream>>>(
            fcbuf, nullptr, nullptr, nullptr, nullptr, nullptr, nullptr,
            Whi_2, Wlo_2, nullptr, nullptr, nullptr, nei, nullptr, p2, 512, 256, 4);
        // conv_out: 256 -> 32. Staging fuses p2 combine + b2/g2/be2 BN+ReLU
        // + residual(dbuf). fp32 partials z=4. grid (256,1,4).
        mconv5<64, 1, 1, 2, false, false, true><<<dim3(256, 1, 4), dim3(64), 0, stream>>>(
            nullptr, nullptr, p2, b2, g2, be2, dbuf,
            Whi_o, Wlo_o, nullptr, nullptr, nullptr, nei, nullptr, pout, 256, 32, 1);
        // finalize: sum partials + bo/go/beo BN+ReLU + feats + norms
        finalize_kern<<<dim3(256), dim3(64), 0, stream>>>(pout, feats, bo, go, beo, oe, oi);
    }

    des2dr_kern<<<dim3(256), dim3(64), 0, stream>>>(out_e0, out_e1, permu, pre_int, out_pr);
    ability_kern<<<dim3(1), dim3(256), 0, stream>>>(pre_int, true_idx, out_ab, out_tr);

    (void)in_sizes; (void)n_in; (void)out_size; (void)ws_size;
}

// Round 9
// 818.167 us; speedup vs baseline: 4.1477x; 1.1406x over previous
//
#include <hip/hip_runtime.h>

#define G60 60
#define KN 13

typedef unsigned int u32;
typedef unsigned short u16;
typedef short short8 __attribute__((ext_vector_type(8)));
typedef float f32x4 __attribute__((ext_vector_type(4)));
typedef float f32x16 __attribute__((ext_vector_type(16)));
typedef u32 u32x4 __attribute__((ext_vector_type(4)));

// compile-time for loop: every index is a literal -> registers guaranteed
template <int I> struct Ic { static constexpr int v = I; };
template <int I, int N, typename F>
__device__ __forceinline__ void sfor(F&& f) {
    if constexpr (I < N) { f(Ic<I>{}); sfor<I + 1, N>(f); }
}

// ---- split-bf16 helpers ----------------------------------------------------
__device__ __forceinline__ u32 f32_to_packed(float v) {
    u32 u = __float_as_uint(v);
    u32 hi = (u + 0x7FFFu + ((u >> 16) & 1u)) >> 16;      // RNE bf16 of v
    float vhi = __uint_as_float(hi << 16);
    float lof = v - vhi;
    u32 ul = __float_as_uint(lof);
    u32 lo = (ul + 0x7FFFu + ((ul >> 16) & 1u)) >> 16;    // RNE bf16 of residual
    return (hi << 16) | lo;
}
__device__ __forceinline__ float packed_f32(u32 w) {
    return __uint_as_float(w & 0xFFFF0000u) + __uint_as_float(w << 16);
}

// ---- fused weight pack: all 4 layers in one dispatch -----------------------
// W[o][c][k] -> 32x32x16 MFMA B-frag order, hi/lo planes.
// chunk t = (ct*13 + kk)*SUBS + sub ; element id = ((t*NTt + nt)*64 + lane)*8 + j
// o = nt*32 + (lane&31); c = ct*CT + sub*16 + (lane>>5)*8 + j
__device__ __forceinline__ void pack_one(const float* __restrict__ W,
                                         u16* __restrict__ Whi, u16* __restrict__ Wlo,
                                         int C, int O, int CT, int id) {
    int j = id & 7;
    int lane = (id >> 3) & 63;
    int fid = id >> 9;
    int NTt = O >> 5;
    int nt = fid % NTt;
    int t = fid / NTt;
    int SUBS = CT >> 4;
    int sub = t % SUBS;
    int kk = (t / SUBS) % KN;
    int ct = t / (KN * SUBS);
    int q = lane >> 5, n = lane & 31;
    int o = nt * 32 + n;
    int c = ct * CT + sub * 16 + q * 8 + j;
    u32 pw = f32_to_packed(W[((size_t)o * C + c) * KN + kk]);
    Whi[id] = (u16)(pw >> 16);
    Wlo[id] = (u16)(pw & 0xFFFFu);
}

__global__ void __launch_bounds__(256) pack_all_kern(
    const float* W_in, u16* Whi_in, u16* Wlo_in,
    const float* W1, u16* Whi_1, u16* Wlo_1,
    const float* W2, u16* Whi_2, u16* Wlo_2,
    const float* Wo, u16* Whi_o, u16* Wlo_o) {
    const int T0 = KN * 32 * 256;            // conv_in (CT=32)
    const int T1 = T0 + KN * 256 * 512;      // conv1
    const int T2 = T1 + KN * 512 * 256;      // conv2
    const int T3 = T2 + KN * 256 * 32;       // conv_out
    int id = blockIdx.x * 256 + threadIdx.x;
    if (id < T0) pack_one(W_in, Whi_in, Wlo_in, 32, 256, 32, id);
    else if (id < T1) pack_one(W1, Whi_1, Wlo_1, 256, 512, 64, id - T0);
    else if (id < T2) pack_one(W2, Whi_2, Wlo_2, 512, 256, 64, id - T1);
    else if (id < T3) pack_one(Wo, Whi_o, Wlo_o, 256, 32, 64, id - T2);
}

// ---- 32x32x16 MFMA comb-conv, batch-paired for W-traffic amortization ------
// Block stages NB batches into LDS; NWN waves (n-split). Each wave computes
// M=64 rows (both m-tiles) for ALL NB batches with ONE B-register fetch
// (W bytes/MFMA = 683/(2*NB)). B double-buffered in regs via static sfor.
// SRC: 0 packed u32, 1 fp32 (pack inline), 2 combine-2-fp32-partials+BN+ReLU
// +packed-residual. OUTF32: fp32 partial plane indexed by blockIdx.z.
template <int CT, int NB, int NTB, int NWN, int SRC, bool BNR, bool OUTF32>
__global__ void __launch_bounds__(NWN * 64, 2) mconv6(
    const u32* __restrict__ Xp, const float* __restrict__ Xf,
    const float* __restrict__ pIn,
    const float* __restrict__ bnb, const float* __restrict__ bng,
    const float* __restrict__ bnB,
    const u32* __restrict__ resid,
    const u16* __restrict__ Whi, const u16* __restrict__ Wlo,
    const float* __restrict__ bias, const float* __restrict__ gamma,
    const float* __restrict__ beta,
    const int* __restrict__ nei,
    u32* __restrict__ outp, float* __restrict__ outf,
    int C, int O, int tpz) {
    constexpr int SUBS = CT >> 4;
    constexpr int S = KN * SUBS;           // K-steps per ct tile
    constexpr int NG = S / 2;              // groups of 2 steps
    constexpr int STRIDE = CT + 8;         // u16; rows 16B-aligned (72 or 40)
    constexpr int PLSZ = G60 * STRIDE;     // u16 per plane (16B-multiple)
    constexpr int THREADS = NWN * 64;
    __shared__ u16 Xs[NB * 2 * PLSZ];
    const int tid = threadIdx.x;
    const int lane = tid & 63;
    const int wv = tid >> 6;               // n-split wave index
    const int q = lane >> 5;
    const int m = lane & 31;
    const int bp = blockIdx.x;             // batch-group
    const int NTt = O >> 5;
    const int nt0 = ((int)blockIdx.y * NWN + wv) * NTB;
    const int ct0 = (int)blockIdx.z * tpz;
    const size_t PLi = (size_t)256 * C * G60;
    float* outfz = OUTF32 ? (outf + (size_t)blockIdx.z * ((size_t)256 * O * G60)) : nullptr;

    int rowoff[2][KN];                     // same for all NB batches (col = f(g))
#pragma unroll
    for (int mt = 0; mt < 2; ++mt) {
        int g = mt * 32 + m;
        int gl = (g < G60) ? g : 0;
#pragma unroll
        for (int kk = 0; kk < KN; ++kk) rowoff[mt][kk] = nei[gl * KN + kk] * STRIDE;
    }

    f32x16 acc[NB][2][NTB];
#pragma unroll
    for (int bb = 0; bb < NB; ++bb)
#pragma unroll
        for (int mt = 0; mt < 2; ++mt)
#pragma unroll
            for (int nt = 0; nt < NTB; ++nt) acc[bb][mt][nt] = (f32x16)(0.f);

    short8 Bh[2][2][NTB], Bl[2][2][NTB];   // [buf][step-in-group][nt]

    for (int ct = ct0; ct < ct0 + tpz; ++ct) {
        const size_t fbase = ((size_t)(ct * S) * NTt + nt0) * 512 + (size_t)lane * 8;

        __syncthreads();
        constexpr int PAIRS = (CT / 2) * G60;
        for (int i = tid; i < NB * PAIRS; i += THREADS) {
            int bb = (NB == 2 && i >= PAIRS) ? 1 : 0;
            int r = i - bb * PAIRS;
            int ccp = (r * 17477) >> 20;   // r/60, exact for r<3840
            int g = r - ccp * G60;
            int cc = ccp * 2;
            size_t cg0 = ((size_t)(bp * NB + bb) * C + (size_t)ct * CT + cc) * G60 + g;
            u32 w0, w1;
            if (SRC == 0) {
                w0 = Xp[cg0]; w1 = Xp[cg0 + G60];
            } else if (SRC == 1) {
                w0 = f32_to_packed(Xf[cg0]); w1 = f32_to_packed(Xf[cg0 + G60]);
            } else {
                int c0 = ct * CT + cc;
                float v0 = pIn[cg0] + pIn[PLi + cg0];
                float v1 = pIn[cg0 + G60] + pIn[PLi + cg0 + G60];
                v0 = fmaxf((v0 + bnb[c0]) * bng[c0] + bnB[c0], 0.f) + packed_f32(resid[cg0]);
                v1 = fmaxf((v1 + bnb[c0 + 1]) * bng[c0 + 1] + bnB[c0 + 1], 0.f) + packed_f32(resid[cg0 + G60]);
                w0 = f32_to_packed(v0); w1 = f32_to_packed(v1);
            }
            int rb = bb * 2 * PLSZ + g * STRIDE + cc;
            *(u32*)(Xs + rb) = (w0 >> 16) | (w1 & 0xFFFF0000u);          // hi plane
            *(u32*)(Xs + rb + PLSZ) = (w0 & 0xFFFFu) | (w1 << 16);       // lo plane
        }

        // group-0 B prefetch issued before the barrier (independent of LDS)
        sfor<0, 2>([&](auto uc) {
            constexpr int u = decltype(uc)::v;
            sfor<0, NTB>([&](auto nc) {
                constexpr int nt = decltype(nc)::v;
                const size_t fb = fbase + ((size_t)u * NTt + nt) * 512;
                Bh[0][u][nt] = *reinterpret_cast<const short8*>(Whi + fb);
                Bl[0][u][nt] = *reinterpret_cast<const short8*>(Wlo + fb);
            });
        });
        __syncthreads();

        sfor<0, NG>([&](auto gc) {
            constexpr int g = decltype(gc)::v;
            constexpr int pb = g & 1;
            if constexpr (g + 1 < NG) {
                constexpr int pn = (g + 1) & 1;
                sfor<0, 2>([&](auto uc) {
                    constexpr int u = decltype(uc)::v;
                    constexpr int s = 2 * (g + 1) + u;
                    sfor<0, NTB>([&](auto nc) {
                        constexpr int nt = decltype(nc)::v;
                        const size_t fb = fbase + ((size_t)s * NTt + nt) * 512;
                        Bh[pn][u][nt] = *reinterpret_cast<const short8*>(Whi + fb);
                        Bl[pn][u][nt] = *reinterpret_cast<const short8*>(Wlo + fb);
                    });
                });
            }
            // A fragments for group g: NB*2 m-rows x 2 planes x 2 steps
            short8 Ah[2][NB][2], Al[2][NB][2];
            sfor<0, 2>([&](auto uc) {
                constexpr int u = decltype(uc)::v;
                constexpr int s = 2 * g + u;
                constexpr int kk = s / SUBS;
                constexpr int sub = s - kk * SUBS;
                sfor<0, NB>([&](auto bc) {
                    constexpr int bb = decltype(bc)::v;
                    sfor<0, 2>([&](auto mc) {
                        constexpr int mt = decltype(mc)::v;
                        const int off = bb * 2 * PLSZ + rowoff[mt][kk] + sub * 16 + q * 8;
                        Ah[u][bb][mt] = *reinterpret_cast<const short8*>(Xs + off);
                        Al[u][bb][mt] = *reinterpret_cast<const short8*>(Xs + off + PLSZ);
                    });
                });
            });
            // MFMAs: 3 passes x NB x 2mt x NTB per step
            sfor<0, 2>([&](auto uc) {
                constexpr int u = decltype(uc)::v;
                sfor<0, NTB>([&](auto nc) {
                    constexpr int nt = decltype(nc)::v;
                    sfor<0, NB>([&](auto bc) {
                        constexpr int bb = decltype(bc)::v;
                        sfor<0, 2>([&](auto mc) {
                            constexpr int mt = decltype(mc)::v;
                            acc[bb][mt][nt] = __builtin_amdgcn_mfma_f32_32x32x16_bf16(
                                Ah[u][bb][mt], Bh[pb][u][nt], acc[bb][mt][nt], 0, 0, 0);
                        });
                    });
                });
                sfor<0, NTB>([&](auto nc) {
                    constexpr int nt = decltype(nc)::v;
                    sfor<0, NB>([&](auto bc) {
                        constexpr int bb = decltype(bc)::v;
                        sfor<0, 2>([&](auto mc) {
                            constexpr int mt = decltype(mc)::v;
                            acc[bb][mt][nt] = __builtin_amdgcn_mfma_f32_32x32x16_bf16(
                                Ah[u][bb][mt], Bl[pb][u][nt], acc[bb][mt][nt], 0, 0, 0);
                        });
                    });
                });
                sfor<0, NTB>([&](auto nc) {
                    constexpr int nt = decltype(nc)::v;
                    sfor<0, NB>([&](auto bc) {
                        constexpr int bb = decltype(bc)::v;
                        sfor<0, 2>([&](auto mc) {
                            constexpr int mt = decltype(mc)::v;
                            acc[bb][mt][nt] = __builtin_amdgcn_mfma_f32_32x32x16_bf16(
                                Al[u][bb][mt], Bh[pb][u][nt], acc[bb][mt][nt], 0, 0, 0);
                        });
                    });
                });
            });
        });
    }

    // epilogue. C/D: col(o)=lane&31, row-in-tile = (r&3)+8*(r>>2)+4*q [m74/m101]
#pragma unroll
    for (int nt = 0; nt < NTB; ++nt) {
        const int o = (nt0 + nt) * 32 + m;
        float bi = 0.f, ga = 1.f, be = 0.f;
        if (!OUTF32) { bi = bias[o]; if (BNR) { ga = gamma[o]; be = beta[o]; } }
#pragma unroll
        for (int bb = 0; bb < NB; ++bb) {
            const int b = bp * NB + bb;
#pragma unroll
            for (int mt = 0; mt < 2; ++mt) {
#pragma unroll
                for (int grp = 0; grp < 4; ++grp) {
                    const int g0 = mt * 32 + grp * 8 + q * 4;
                    if (g0 < G60) {
                        size_t oi = ((size_t)b * O + o) * G60 + g0;
                        if (OUTF32) {
                            f32x4 v;
#pragma unroll
                            for (int rr = 0; rr < 4; ++rr) v[rr] = acc[bb][mt][nt][grp * 4 + rr];
                            *reinterpret_cast<f32x4*>(outfz + oi) = v;
                        } else {
                            u32x4 pv;
#pragma unroll
                            for (int rr = 0; rr < 4; ++rr) {
                                float v = acc[bb][mt][nt][grp * 4 + rr] + bi;
                                if (BNR) v = fmaxf(v * ga + be, 0.f);
                                pv[rr] = f32_to_packed(v);
                            }
                            *reinterpret_cast<u32x4*>(outp + oi) = pv;
                        }
                    }
                }
            }
        }
    }
}

// ---- finalize: sum 4 conv_out partials, BN+ReLU, +feats, norms; also emits
// the feats passthrough output (replaces the d2d memcpy dispatch). -----------
__global__ void __launch_bounds__(64) finalize_kern(
    const float* __restrict__ pout,          // [4][B][32][60] fp32 partials
    const float* __restrict__ feats,         // [B][32][60]
    const float* __restrict__ bo, const float* __restrict__ go,
    const float* __restrict__ beo,
    float* __restrict__ out_feats,           // [B][32][60] passthrough
    float* __restrict__ out_eqv,             // [B][32][60]
    float* __restrict__ out_inv) {           // [B][32]
    const int b = blockIdx.x;
    const size_t PB = (size_t)256 * 32 * G60;
    __shared__ float E[32 * G60];
    __shared__ float gnorm[G60];
    __shared__ float inv_pre[32];
    __shared__ float inv_nrm;
    const int tid = threadIdx.x;

    for (int i = tid; i < 32 * G60; i += 64) {
        int f = i / G60;
        size_t idx = (size_t)b * 1920 + i;
        float ft = feats[idx];
        out_feats[idx] = ft;
        float s = pout[idx] + pout[PB + idx] + pout[2 * PB + idx] + pout[3 * PB + idx];
        float v = fmaxf((s + bo[f]) * go[f] + beo[f], 0.f);
        E[i] = v + ft;
    }
    __syncthreads();
    if (tid < G60) {
        float s = 0.f;
        for (int f = 0; f < 32; ++f) { float v = E[f * G60 + tid]; s += v * v; }
        gnorm[tid] = fmaxf(sqrtf(s), 1e-4f);
    }
    if (tid < 32) {
        float s = 0.f;
        for (int g = 0; g < G60; ++g) s += E[tid * G60 + g];
        inv_pre[tid] = s / 60.f;
    }
    __syncthreads();
    if (tid == 0) {
        float s = 0.f;
        for (int f = 0; f < 32; ++f) s += inv_pre[f] * inv_pre[f];
        inv_nrm = fmaxf(sqrtf(s), 1e-4f);
    }
    __syncthreads();
    for (int i = tid; i < 1920; i += 64) {
        int g = i % G60;
        out_eqv[(size_t)b * 1920 + i] = E[i] / gnorm[g];
    }
    if (tid < 32) out_inv[b * 32 + tid] = inv_pre[tid] / inv_nrm;
}

// ---- des2dr: 256 thr/block, 4-way channel split per rotation a -------------
__global__ void __launch_bounds__(256) des2dr_kern(
    const float* __restrict__ e0f, const float* __restrict__ e1f,
    const int* __restrict__ permu, int* __restrict__ pre_int,
    float* __restrict__ out_pre) {
    const int b = blockIdx.x;
    __shared__ float X0[32 * G60];
    __shared__ float X1[32 * G60];
    __shared__ float pc[256];
    __shared__ float cor[64];
    const int tid = threadIdx.x;
    for (int i = tid; i < 1920; i += 256) {
        X0[i] = e0f[(size_t)b * 1920 + i];
        X1[i] = e1f[(size_t)b * 1920 + i];
    }
    __syncthreads();
    const int a = tid >> 2, fc = tid & 3;
    float s = 0.f;
    if (a < G60) {
        for (int g = 0; g < G60; ++g) {
            int p = permu[a * G60 + g];
#pragma unroll
            for (int f = fc * 8; f < fc * 8 + 8; ++f) s += X0[f * G60 + p] * X1[f * G60 + g];
        }
    }
    pc[tid] = s;
    __syncthreads();
    if (tid < 64) cor[tid] = pc[4 * tid] + pc[4 * tid + 1] + pc[4 * tid + 2] + pc[4 * tid + 3];
    __syncthreads();
    if (tid == 0) {
        float best = cor[0];
        int bi = 0;
        for (int a2 = 1; a2 < G60; ++a2)
            if (cor[a2] > best) { best = cor[a2]; bi = a2; }  // first-max = jnp.argmax
        pre_int[b] = bi;
        out_pre[b] = (float)bi;
    }
}

__global__ void __launch_bounds__(256) ability_kern(
    const int* __restrict__ pre_int, const int* __restrict__ true_idx,
    float* __restrict__ out_ability, float* __restrict__ out_true) {
    __shared__ int cnt[256];
    const int t = threadIdx.x;
    cnt[t] = (pre_int[t] == true_idx[t]) ? 1 : 0;
    out_true[t] = (float)true_idx[t];
    __syncthreads();
    for (int s = 128; s > 0; s >>= 1) {
        if (t < s) cnt[t] += cnt[t + s];
        __syncthreads();
    }
    if (t == 0) out_ability[0] = (float)cnt[0] / 256.0f;
}

extern "C" void kernel_launch(void* const* d_in, const int* in_sizes, int n_in,
                              void* d_out, int out_size, void* d_ws, size_t ws_size,
                              hipStream_t stream) {
    const float* feats0 = (const float*)d_in[0];
    const float* feats1 = (const float*)d_in[1];
    const int* true_idx = (const int*)d_in[2];
    const int* nei = (const int*)d_in[3];
    const int* permu = (const int*)d_in[4];
    const float* W_in = (const float*)d_in[5];
    const float* b_in = (const float*)d_in[6];
    const float* W1 = (const float*)d_in[7];
    const float* b1 = (const float*)d_in[8];
    const float* g1 = (const float*)d_in[9];
    const float* be1 = (const float*)d_in[10];
    const float* W2 = (const float*)d_in[11];
    const float* b2 = (const float*)d_in[12];
    const float* g2 = (const float*)d_in[13];
    const float* be2 = (const float*)d_in[14];
    const float* Wo = (const float*)d_in[15];
    const float* bo = (const float*)d_in[16];
    const float* go = (const float*)d_in[17];
    const float* beo = (const float*)d_in[18];

    float* out = (float*)d_out;
    const size_t SZF = (size_t)256 * 32 * G60;  // 491520
    float* out_f0 = out;
    float* out_f1 = out + SZF;
    float* out_e0 = out + 2 * SZF;
    float* out_e1 = out + 3 * SZF;
    float* out_i0 = out + 4 * SZF;
    float* out_i1 = out_i0 + 256 * 32;
    float* out_ab = out_i1 + 256 * 32;
    float* out_tr = out_ab + 1;
    float* out_pr = out_tr + 256;

    // ---- workspace layout (~101 MB, unchanged footprint) ----
    char* p = (char*)d_ws;
    auto alloc = [&](size_t bytes) { char* r = p; p += (bytes + 255) & ~(size_t)255; return r; };
    const size_t NW_IN = (size_t)KN * 32 * 256;
    const size_t NW_1 = (size_t)KN * 256 * 512;
    const size_t NW_2 = (size_t)KN * 512 * 256;
    const size_t NW_O = (size_t)KN * 256 * 32;
    u16* Whi_in = (u16*)alloc(NW_IN * 2); u16* Wlo_in = (u16*)alloc(NW_IN * 2);
    u16* Whi_1 = (u16*)alloc(NW_1 * 2);   u16* Wlo_1 = (u16*)alloc(NW_1 * 2);
    u16* Whi_2 = (u16*)alloc(NW_2 * 2);   u16* Wlo_2 = (u16*)alloc(NW_2 * 2);
    u16* Whi_o = (u16*)alloc(NW_O * 2);   u16* Wlo_o = (u16*)alloc(NW_O * 2);
    u32* dbuf = (u32*)alloc((size_t)256 * 256 * G60 * 4);        // conv_in out, packed
    u32* fcbuf = (u32*)alloc((size_t)256 * 512 * G60 * 4);       // conv1 out, packed
    float* p2 = (float*)alloc((size_t)2 * 256 * 256 * G60 * 4);  // conv2 K-split partials
    float* pout = (float*)alloc((size_t)4 * SZF * 4);            // conv_out K-split partials
    int* pre_int = (int*)alloc(256 * 4);

    // ---- fused weight pack (1 dispatch) ----
    {
        int total = KN * (32 * 256 + 256 * 512 + 512 * 256 + 256 * 32);
        pack_all_kern<<<dim3((total + 255) / 256), dim3(256), 0, stream>>>(
            W_in, Whi_in, Wlo_in, W1, Whi_1, Wlo_1, W2, Whi_2, Wlo_2, Wo, Whi_o, Wlo_o);
    }

    for (int net = 0; net < 2; ++net) {
        const float* feats = net ? feats1 : feats0;
        float* of = net ? out_f1 : out_f0;
        float* oe = net ? out_e1 : out_e0;
        float* oi = net ? out_i1 : out_i0;

        // conv_in: 32 -> 256, fp32 src packed inline. NB=1, NTB=1, NWN=4.
        // grid (256, 2): 512 blocks, 8 waves/CU.
        mconv6<32, 1, 1, 4, 1, false, false><<<dim3(256, 2, 1), dim3(256), 0, stream>>>(
            nullptr, feats, nullptr, nullptr, nullptr, nullptr, nullptr,
            Whi_in, Wlo_in, b_in, nullptr, nullptr, nei, dbuf, nullptr, 32, 256, 1);
        // conv1: 256 -> 512, BN+ReLU packed. NB=2 (batch-paired W amortization),
        // NTB=1, NWN=4. grid (128, 4): 512 blocks, 8 waves/CU, W traffic halved.
        mconv6<64, 2, 1, 4, 0, true, false><<<dim3(128, 4, 1), dim3(256), 0, stream>>>(
            dbuf, nullptr, nullptr, nullptr, nullptr, nullptr, nullptr,
            Whi_1, Wlo_1, b1, g1, be1, nei, fcbuf, nullptr, 256, 512, 4);
        // conv2: 512 -> 256, fp32 partials, z=2 K-split. NB=2. grid (128, 2, 2).
        mconv6<64, 2, 1, 4, 0, false, true><<<dim3(128, 2, 2), dim3(256), 0, stream>>>(
            fcbuf, nullptr, nullptr, nullptr, nullptr, nullptr, nullptr,
            Whi_2, Wlo_2, nullptr, nullptr, nullptr, nei, nullptr, p2, 512, 256, 4);
        // conv_out: 256 -> 32. Staging fuses p2 combine + b2/g2/be2 BN+ReLU
        // + residual(dbuf). fp32 partials z=4. NB=2, NWN=1. grid (128, 1, 4).
        mconv6<64, 2, 1, 1, 2, false, true><<<dim3(128, 1, 4), dim3(64), 0, stream>>>(
            nullptr, nullptr, p2, b2, g2, be2, dbuf,
            Whi_o, Wlo_o, nullptr, nullptr, nullptr, nei, nullptr, pout, 256, 32, 1);
        // finalize: sum partials + bo/go/beo BN+ReLU + feats + norms + passthrough
        finalize_kern<<<dim3(256), dim3(64), 0, stream>>>(pout, feats, bo, go, beo, of, oe, oi);
    }

    des2dr_kern<<<dim3(256), dim3(256), 0, stream>>>(out_e0, out_e1, permu, pre_int, out_pr);
    ability_kern<<<dim3(1), dim3(256), 0, stream>>>(pre_int, true_idx, out_ab, out_tr);

    (void)in_sizes; (void)n_in; (void)out_size; (void)ws_size;
}